// Round 1
// baseline (4974.746 us; speedup 1.0000x reference)
//
#include <hip/hip_runtime.h>
#include <hip/hip_bf16.h>
#include <math.h>

// ---------------------------------------------------------------------------
// BinaryCNN: conv(wq)->bn->ht x5 (pools after conv2,3,4), fc->bn->ht x2, fc3.
// Round 1: correct fp32 baseline. BN folded to per-channel A,B. Weights
// fake-quantized on device each launch (no cross-launch state).
// ---------------------------------------------------------------------------

#define EPS 1e-5f

// ---------------- weight fake-quant: per-output-channel ----------------
struct QuantArgs {
  const float* w[8];
  float* q[8];
  int cik[8];
  int cum[9];
};

__global__ __launch_bounds__(256) void quant_all(QuantArgs a) {
  int b = blockIdx.x;
  int t = 0;
  while (b >= a.cum[t + 1]) t++;
  int co = b - a.cum[t];
  int cik = a.cik[t];
  const float* src = a.w[t] + (size_t)co * cik;
  float* dst = a.q[t] + (size_t)co * cik;
  float m = 0.f;
  for (int i = threadIdx.x; i < cik; i += 256) m = fmaxf(m, fabsf(src[i]));
  #pragma unroll
  for (int o = 1; o < 64; o <<= 1) m = fmaxf(m, __shfl_xor(m, o));
  __shared__ float red[4];
  __shared__ float ssh;
  if ((threadIdx.x & 63) == 0) red[threadIdx.x >> 6] = m;
  __syncthreads();
  if (threadIdx.x == 0) {
    m = fmaxf(fmaxf(red[0], red[1]), fmaxf(red[2], red[3]));
    ssh = fmaxf(m / 127.0f, 1e-8f);
  }
  __syncthreads();
  float s = ssh;
  for (int i = threadIdx.x; i < cik; i += 256) {
    float q = rintf(src[i] / s);               // round half to even, like jnp.round
    q = fminf(fmaxf(q, -128.f), 127.f);
    dst[i] = q * s;
  }
}

// ---------------- fold BN (+conv bias) into per-channel A,B ----------------
struct BnArgs {
  const float* p[7][5];   // b, g, be, mu, va
  float* ab;
  int C[7];
  int abo[7];
  int cum[8];
};

__global__ __launch_bounds__(256) void bn_all(BnArgs a) {
  int i = blockIdx.x * 256 + threadIdx.x;
  if (i >= a.cum[7]) return;
  int t = 0;
  while (i >= a.cum[t + 1]) t++;
  int c = i - a.cum[t];
  float A = a.p[t][1][c] / sqrtf(a.p[t][4][c] + EPS);
  float B = (a.p[t][0][c] - a.p[t][3][c]) * A + a.p[t][2][c];
  a.ab[a.abo[t] + c] = A;
  a.ab[a.abo[t] + a.C[t] + c] = B;
}

// ---------------- generic conv+pool+bn+ht (block per image) ----------------
// Weights staged in LDS (padded rows for b128 reads); input via L1.
// Work item = (pooled pixel, register-group of GOC_R output channels).
template <int CIN, int COUT, int K, int PAD, int IN_W, int POOL, int GOC_S, int GOC_R>
__global__ __launch_bounds__(256, 2) void conv_bn_ht_A(
    const float* __restrict__ in, const float* __restrict__ wq,
    const float* __restrict__ ab, float* __restrict__ out) {
  constexpr int KK = K * K;
  constexpr int WSTR = (KK + 3) & ~3;          // pad to 16B rows
  constexpr int PW = IN_W / POOL;
  constexpr int NPIX = PW * PW;
  constexpr int WIN = K + POOL - 1;
  constexpr int NGRP = GOC_S / GOC_R;
  constexpr int NITEM = NPIX * NGRP;
  __shared__ __align__(16) float sw[GOC_S * CIN * WSTR];
  const int img = blockIdx.x;
  const float* __restrict__ gx = in + (size_t)img * CIN * IN_W * IN_W;
  for (int os = 0; os < COUT; os += GOC_S) {
    __syncthreads();
    for (int li = threadIdx.x; li < GOC_S * CIN * KK; li += 256) {
      int ol = li / (CIN * KK);
      int r = li - ol * CIN * KK;
      int ci = r / KK;
      int kk = r - ci * KK;
      sw[(ol * CIN + ci) * WSTR + kk] = wq[((size_t)(os + ol) * CIN + ci) * KK + kk];
    }
    __syncthreads();
    for (int it = threadIdx.x; it < NITEM; it += 256) {
      const int p = it % NPIX;
      const int g = it / NPIX;
      const int py = p / PW, px = p - py * PW;
      const int oy0 = py * POOL - PAD, ox0 = px * POOL - PAD;
      float acc[GOC_R][POOL * POOL];
      #pragma unroll
      for (int j = 0; j < GOC_R; ++j)
        #pragma unroll
        for (int q = 0; q < POOL * POOL; ++q) acc[j][q] = 0.f;
      for (int ci = 0; ci < CIN; ++ci) {
        float win[WIN * WIN];
        #pragma unroll
        for (int r = 0; r < WIN; ++r) {
          const int iy = oy0 + r;
          const bool oky = (iy >= 0) && (iy < IN_W);
          #pragma unroll
          for (int c = 0; c < WIN; ++c) {
            const int ix = ox0 + c;
            win[r * WIN + c] = (oky && ix >= 0 && ix < IN_W)
                                   ? gx[(ci * IN_W + iy) * IN_W + ix] : 0.f;
          }
        }
        #pragma unroll
        for (int j = 0; j < GOC_R; ++j) {
          const float* wp = sw + ((g * GOC_R + j) * CIN + ci) * WSTR;
          float wr[KK];
          #pragma unroll
          for (int kk = 0; kk < KK; ++kk) wr[kk] = wp[kk];
          #pragma unroll
          for (int ky = 0; ky < K; ++ky)
            #pragma unroll
            for (int kx = 0; kx < K; ++kx)
              #pragma unroll
              for (int dy = 0; dy < POOL; ++dy)
                #pragma unroll
                for (int dx = 0; dx < POOL; ++dx)
                  acc[j][dy * POOL + dx] +=
                      win[(ky + dy) * WIN + (kx + dx)] * wr[ky * K + kx];
        }
      }
      #pragma unroll
      for (int j = 0; j < GOC_R; ++j) {
        const int oc = os + g * GOC_R + j;
        float m = acc[j][0];
        #pragma unroll
        for (int q = 1; q < POOL * POOL; ++q) m = fmaxf(m, acc[j][q]);
        float v = m * ab[oc] + ab[COUT + oc];
        v = fminf(fmaxf(v, -1.f), 1.f);
        out[((size_t)img * COUT + oc) * NPIX + p] = v;
      }
    }
  }
}

// ---------------- small-input conv (thread per output channel) ----------------
// COUT must equal 256 (= blockDim). Input loads are wave-uniform (broadcast).
template <int CIN, int COUT, int K, int PAD, int IN_W, int POOL, int CCH>
__global__ __launch_bounds__(256, 2) void conv_bn_ht_B(
    const float* __restrict__ in, const float* __restrict__ wq,
    const float* __restrict__ ab, float* __restrict__ out) {
  constexpr int KK = K * K;
  constexpr int OW = IN_W + 2 * PAD - K + 1;
  constexpr int PW = OW / POOL;
  constexpr int UW = PW * POOL;                // conv pixels actually used
  constexpr int INN = IN_W * IN_W;
  __shared__ float sw[CCH * COUT * KK];        // [ci][oc][kk]
  const int img = blockIdx.x;
  const int oc = threadIdx.x;
  const float* __restrict__ gx = in + (size_t)img * CIN * INN;
  float acc[UW * UW];
  #pragma unroll
  for (int q = 0; q < UW * UW; ++q) acc[q] = 0.f;
  for (int c0 = 0; c0 < CIN; c0 += CCH) {
    __syncthreads();
    for (int li = threadIdx.x; li < COUT * CCH * KK; li += 256) {
      int o = li / (CCH * KK);
      int r = li - o * (CCH * KK);
      int ci = r / KK;
      int kk = r - ci * KK;
      sw[(ci * COUT + o) * KK + kk] = wq[((size_t)o * CIN + (c0 + ci)) * KK + kk];
    }
    __syncthreads();
    #pragma unroll
    for (int ci = 0; ci < CCH; ++ci) {
      float win[INN];
      #pragma unroll
      for (int q = 0; q < INN; ++q) win[q] = gx[(c0 + ci) * INN + q];
      float wr[KK];
      #pragma unroll
      for (int kk = 0; kk < KK; ++kk) wr[kk] = sw[(ci * COUT + oc) * KK + kk];
      #pragma unroll
      for (int oy = 0; oy < UW; ++oy)
        #pragma unroll
        for (int ox = 0; ox < UW; ++ox)
          #pragma unroll
          for (int ky = 0; ky < K; ++ky)
            #pragma unroll
            for (int kx = 0; kx < K; ++kx) {
              constexpr int dummy = 0; (void)dummy;
              const int iy = oy + ky - PAD, ix = ox + kx - PAD;
              if (iy >= 0 && iy < IN_W && ix >= 0 && ix < IN_W)
                acc[oy * UW + ox] += win[iy * IN_W + ix] * wr[ky * K + kx];
            }
    }
  }
  const float A = ab[oc], Bc = ab[COUT + oc];
  #pragma unroll
  for (int py = 0; py < PW; ++py)
    #pragma unroll
    for (int px = 0; px < PW; ++px) {
      float m = -INFINITY;
      #pragma unroll
      for (int dy = 0; dy < POOL; ++dy)
        #pragma unroll
        for (int dx = 0; dx < POOL; ++dx)
          m = fmaxf(m, acc[(py * POOL + dy) * UW + px * POOL + dx]);
      float v = fminf(fmaxf(m * A + Bc, -1.f), 1.f);
      out[((size_t)img * COUT + oc) * (PW * PW) + py * PW + px] = v;
    }
}

// ---------------- FC gemm + bn + ht: C[M,N] = X[M,K] . W[N,K]^T ----------------
__global__ __launch_bounds__(256, 2) void fc_bn_ht(
    const float* __restrict__ X, const float* __restrict__ W,
    const float* __restrict__ ab, float* __restrict__ out,
    int M, int N, int K, int doHt) {
  __shared__ __align__(16) float Xs[16][64];
  __shared__ __align__(16) float Ws[16][64];
  const int bm = blockIdx.y * 64, bn = blockIdx.x * 64;
  const int tx = threadIdx.x & 15, ty = threadIdx.x >> 4;
  const int lr = threadIdx.x >> 2, lc = (threadIdx.x & 3) * 4;
  float acc[4][4];
  #pragma unroll
  for (int i = 0; i < 4; ++i)
    #pragma unroll
    for (int j = 0; j < 4; ++j) acc[i][j] = 0.f;
  const float* xp = X + (size_t)(bm + lr) * K + lc;
  const float* wp = W + (size_t)(bn + lr) * K + lc;
  for (int k0 = 0; k0 < K; k0 += 16) {
    const float4 xv = *(const float4*)(xp + k0);
    const float4 wv = *(const float4*)(wp + k0);
    __syncthreads();
    Xs[lc + 0][lr] = xv.x; Xs[lc + 1][lr] = xv.y;
    Xs[lc + 2][lr] = xv.z; Xs[lc + 3][lr] = xv.w;
    Ws[lc + 0][lr] = wv.x; Ws[lc + 1][lr] = wv.y;
    Ws[lc + 2][lr] = wv.z; Ws[lc + 3][lr] = wv.w;
    __syncthreads();
    #pragma unroll
    for (int kk = 0; kk < 16; ++kk) {
      const float4 a = *(const float4*)(&Xs[kk][tx * 4]);
      const float4 b = *(const float4*)(&Ws[kk][ty * 4]);
      const float av[4] = {a.x, a.y, a.z, a.w};
      const float bv[4] = {b.x, b.y, b.z, b.w};
      #pragma unroll
      for (int i = 0; i < 4; ++i)
        #pragma unroll
        for (int j = 0; j < 4; ++j) acc[i][j] += av[i] * bv[j];
    }
  }
  #pragma unroll
  for (int i = 0; i < 4; ++i) {
    const int m = bm + tx * 4 + i;
    #pragma unroll
    for (int j = 0; j < 4; ++j) {
      const int n = bn + ty * 4 + j;
      float v = acc[i][j] * ab[n] + ab[N + n];
      if (doHt) v = fminf(fmaxf(v, -1.f), 1.f);
      out[(size_t)m * N + n] = v;
    }
  }
}

// ---------------- FC3: [1024,512] x [10,512]^T + bias ----------------
__global__ __launch_bounds__(256) void fc3_kernel(
    const float* __restrict__ X, const float* __restrict__ W,
    const float* __restrict__ bias, float* __restrict__ out) {
  __shared__ float ws[512 * 10 + 16];          // transposed [k][n]
  for (int li = threadIdx.x; li < 5120; li += 256) {
    int n = li / 512, k = li - n * 512;
    ws[k * 10 + n] = W[li];
  }
  __syncthreads();
  const int il = threadIdx.x >> 4, n = threadIdx.x & 15;
  const int img = blockIdx.x * 16 + il;
  if (n < 10) {
    const float* xp = X + (size_t)img * 512;
    float s = 0.f;
    for (int k = 0; k < 512; ++k) s += xp[k] * ws[k * 10 + n];
    out[img * 10 + n] = s + bias[n];
  }
}

// ---------------- launch ----------------
extern "C" void kernel_launch(void* const* d_in, const int* in_sizes, int n_in,
                              void* d_out, int out_size, void* d_ws, size_t ws_size,
                              hipStream_t stream) {
  (void)in_sizes; (void)n_in; (void)out_size; (void)ws_size;
  const float* x = (const float*)d_in[0];
  float* W = (float*)d_ws;

  // workspace layout (floats, 64-float aligned)
  float* wq1 = W + 0;            // 800
  float* wq2 = W + 832;          // 51200
  float* wq3 = W + 52032;        // 73728
  float* wq4 = W + 125760;       // 294912
  float* wq5 = W + 420672;       // 65536
  float* fq1 = W + 486208;       // 2359296
  float* fq2 = W + 2845504;      // 524288
  float* fq3 = W + 3369792;      // 5120
  float* ab  = W + 3374912;      // 4544
  float* bufA = W + 3379456;     // 25690112 (h1/h3/h5/f2)
  float* bufB = W + 29069568;    // 12845056 (h2/h4/f1)

  // 1) fake-quant all weights
  QuantArgs qa;
  const int widx[8] = {1, 7, 13, 19, 25, 31, 37, 43};
  float* qdst[8] = {wq1, wq2, wq3, wq4, wq5, fq1, fq2, fq3};
  const int cik[8] = {25, 800, 576, 1152, 256, 2304, 1024, 512};
  const int co[8] = {32, 64, 128, 256, 256, 1024, 512, 10};
  int cum = 0;
  for (int i = 0; i < 8; ++i) {
    qa.w[i] = (const float*)d_in[widx[i]];
    qa.q[i] = qdst[i];
    qa.cik[i] = cik[i];
    qa.cum[i] = cum;
    cum += co[i];
  }
  qa.cum[8] = cum;                      // 2282
  hipLaunchKernelGGL(quant_all, dim3(cum), dim3(256), 0, stream, qa);

  // 2) fold BN params
  BnArgs ba;
  const int bbase[7] = {2, 8, 14, 20, 26, 32, 38};
  const int bc[7] = {32, 64, 128, 256, 256, 1024, 512};
  const int abo[7] = {0, 64, 192, 448, 960, 1472, 3520};
  int bcum = 0;
  for (int t = 0; t < 7; ++t) {
    for (int j = 0; j < 5; ++j) ba.p[t][j] = (const float*)d_in[bbase[t] + j];
    ba.C[t] = bc[t];
    ba.abo[t] = abo[t];
    ba.cum[t] = bcum;
    bcum += bc[t];
  }
  ba.cum[7] = bcum;                     // 2272
  ba.ab = ab;
  hipLaunchKernelGGL(bn_all, dim3((bcum + 255) / 256), dim3(256), 0, stream, ba);

  // 3) conv stack
  hipLaunchKernelGGL((conv_bn_ht_A<1, 32, 5, 2, 28, 1, 32, 4>), dim3(1024), dim3(256), 0, stream,
                     x, wq1, ab + 0, bufA);                       // h1 [B,32,28,28]
  hipLaunchKernelGGL((conv_bn_ht_A<32, 64, 5, 2, 28, 2, 16, 4>), dim3(1024), dim3(256), 0, stream,
                     bufA, wq2, ab + 64, bufB);                   // h2 [B,64,14,14]
  hipLaunchKernelGGL((conv_bn_ht_A<64, 128, 3, 1, 14, 2, 16, 2>), dim3(1024), dim3(256), 0, stream,
                     bufB, wq3, ab + 192, bufA);                  // h3 [B,128,7,7]
  hipLaunchKernelGGL((conv_bn_ht_B<128, 256, 3, 1, 7, 2, 4>), dim3(1024), dim3(256), 0, stream,
                     bufA, wq4, ab + 448, bufB);                  // h4 [B,256,3,3]
  hipLaunchKernelGGL((conv_bn_ht_B<256, 256, 1, 0, 3, 1, 16>), dim3(1024), dim3(256), 0, stream,
                     bufB, wq5, ab + 960, bufA);                  // h5 [B,256,3,3]=[B,2304]

  // 4) FC stack
  hipLaunchKernelGGL(fc_bn_ht, dim3(1024 / 64, 1024 / 64), dim3(256), 0, stream,
                     bufA, fq1, ab + 1472, bufB, 1024, 1024, 2304, 1);
  hipLaunchKernelGGL(fc_bn_ht, dim3(512 / 64, 1024 / 64), dim3(256), 0, stream,
                     bufB, fq2, ab + 3520, bufA, 1024, 512, 1024, 1);
  hipLaunchKernelGGL(fc3_kernel, dim3(64), dim3(256), 0, stream,
                     bufA, fq3, (const float*)d_in[44], (float*)d_out);
}

// Round 2
// 1400.674 us; speedup vs baseline: 3.5517x; 3.5517x over previous
//
#include <hip/hip_runtime.h>
#include <hip/hip_bf16.h>
#include <math.h>

// ---------------------------------------------------------------------------
// BinaryCNN round 2: conv2/3/4 -> bf16 MFMA implicit GEMM (16x16x32),
// NHWC activations, pooled-pixel-major M so pool+bn+ht is in-register.
// conv1 stays fp32 (1.3 GF), conv5 becomes NHWC 1x1 GEMM, FC fp32 unchanged.
// ---------------------------------------------------------------------------

#define EPS 1e-5f

typedef __attribute__((ext_vector_type(8))) short bf16x8;
typedef __attribute__((ext_vector_type(4))) float f32x4;

__device__ __forceinline__ short f2bf(float f) {
  unsigned u = __builtin_bit_cast(unsigned, f);
  unsigned r = u + 0x7FFFu + ((u >> 16) & 1u);   // RNE
  return (short)(r >> 16);
}

// ---------------- weight fake-quant: per-output-channel ----------------
struct QuantArgs {
  const float* w[8];
  float* q[8];
  int cik[8];
  int cum[9];
};

__global__ __launch_bounds__(256) void quant_all(QuantArgs a) {
  int b = blockIdx.x;
  int t = 0;
  while (b >= a.cum[t + 1]) t++;
  int co = b - a.cum[t];
  int cik = a.cik[t];
  const float* src = a.w[t] + (size_t)co * cik;
  float* dst = a.q[t] + (size_t)co * cik;
  float m = 0.f;
  for (int i = threadIdx.x; i < cik; i += 256) m = fmaxf(m, fabsf(src[i]));
  #pragma unroll
  for (int o = 1; o < 64; o <<= 1) m = fmaxf(m, __shfl_xor(m, o));
  __shared__ float red[4];
  __shared__ float ssh;
  if ((threadIdx.x & 63) == 0) red[threadIdx.x >> 6] = m;
  __syncthreads();
  if (threadIdx.x == 0) {
    m = fmaxf(fmaxf(red[0], red[1]), fmaxf(red[2], red[3]));
    ssh = fmaxf(m / 127.0f, 1e-8f);
  }
  __syncthreads();
  float s = ssh;
  for (int i = threadIdx.x; i < cik; i += 256) {
    float q = rintf(src[i] / s);               // round half to even, like jnp.round
    q = fminf(fmaxf(q, -128.f), 127.f);
    dst[i] = q * s;
  }
}

// ---------------- repack conv weights: fp32 [oc][ci][kk] -> bf16 [kk][oc][ci] ---
__global__ __launch_bounds__(256) void repack_w(const float* __restrict__ src,
                                                short* __restrict__ dst,
                                                int CO, int CI, int KK) {
  int i = blockIdx.x * 256 + threadIdx.x;
  if (i >= CO * CI * KK) return;
  int oc = i / (CI * KK);
  int r = i - oc * (CI * KK);
  int ci = r / KK;
  int kk = r - ci * KK;
  dst[((size_t)kk * CO + oc) * CI + ci] = f2bf(src[i]);
}

// ---------------- transpose w5: [oc][ci] -> [ci][oc] (fp32) ----------------
__global__ __launch_bounds__(256) void transpose_w5(const float* __restrict__ src,
                                                    float* __restrict__ dst) {
  int i = blockIdx.x * 256 + threadIdx.x;    // 65536
  int oc = i >> 8, ci = i & 255;
  dst[ci * 256 + oc] = src[i];
}

// ---------------- fold BN (+conv bias) into per-channel A,B ----------------
struct BnArgs {
  const float* p[7][5];   // b, g, be, mu, va
  float* ab;
  int C[7];
  int abo[7];
  int cum[8];
};

__global__ __launch_bounds__(256) void bn_all(BnArgs a) {
  int i = blockIdx.x * 256 + threadIdx.x;
  if (i >= a.cum[7]) return;
  int t = 0;
  while (i >= a.cum[t + 1]) t++;
  int c = i - a.cum[t];
  float A = a.p[t][1][c] / sqrtf(a.p[t][4][c] + EPS);
  float B = (a.p[t][0][c] - a.p[t][3][c]) * A + a.p[t][2][c];
  a.ab[a.abo[t] + c] = A;
  a.ab[a.abo[t] + a.C[t] + c] = B;
}

// ---------------- conv1: fp32 direct (cheap), NHWC store ----------------
template <int CIN, int COUT, int K, int PAD, int IN_W, int POOL, int GOC_S, int GOC_R>
__global__ __launch_bounds__(256, 2) void conv_bn_ht_A(
    const float* __restrict__ in, const float* __restrict__ wq,
    const float* __restrict__ ab, float* __restrict__ out) {
  constexpr int KK = K * K;
  constexpr int WSTR = (KK + 3) & ~3;
  constexpr int PW = IN_W / POOL;
  constexpr int NPIX = PW * PW;
  constexpr int WIN = K + POOL - 1;
  constexpr int NGRP = GOC_S / GOC_R;
  constexpr int NITEM = NPIX * NGRP;
  __shared__ __align__(16) float sw[GOC_S * CIN * WSTR];
  const int img = blockIdx.x;
  const float* __restrict__ gx = in + (size_t)img * CIN * IN_W * IN_W;
  for (int os = 0; os < COUT; os += GOC_S) {
    __syncthreads();
    for (int li = threadIdx.x; li < GOC_S * CIN * KK; li += 256) {
      int ol = li / (CIN * KK);
      int r = li - ol * CIN * KK;
      int ci = r / KK;
      int kk = r - ci * KK;
      sw[(ol * CIN + ci) * WSTR + kk] = wq[((size_t)(os + ol) * CIN + ci) * KK + kk];
    }
    __syncthreads();
    for (int it = threadIdx.x; it < NITEM; it += 256) {
      const int p = it % NPIX;
      const int g = it / NPIX;
      const int py = p / PW, px = p - py * PW;
      const int oy0 = py * POOL - PAD, ox0 = px * POOL - PAD;
      float acc[GOC_R][POOL * POOL];
      #pragma unroll
      for (int j = 0; j < GOC_R; ++j)
        #pragma unroll
        for (int q = 0; q < POOL * POOL; ++q) acc[j][q] = 0.f;
      for (int ci = 0; ci < CIN; ++ci) {
        float win[WIN * WIN];
        #pragma unroll
        for (int r = 0; r < WIN; ++r) {
          const int iy = oy0 + r;
          const bool oky = (iy >= 0) && (iy < IN_W);
          #pragma unroll
          for (int c = 0; c < WIN; ++c) {
            const int ix = ox0 + c;
            win[r * WIN + c] = (oky && ix >= 0 && ix < IN_W)
                                   ? gx[(ci * IN_W + iy) * IN_W + ix] : 0.f;
          }
        }
        #pragma unroll
        for (int j = 0; j < GOC_R; ++j) {
          const float* wp = sw + ((g * GOC_R + j) * CIN + ci) * WSTR;
          float wr[KK];
          #pragma unroll
          for (int kk = 0; kk < KK; ++kk) wr[kk] = wp[kk];
          #pragma unroll
          for (int ky = 0; ky < K; ++ky)
            #pragma unroll
            for (int kx = 0; kx < K; ++kx)
              #pragma unroll
              for (int dy = 0; dy < POOL; ++dy)
                #pragma unroll
                for (int dx = 0; dx < POOL; ++dx)
                  acc[j][dy * POOL + dx] +=
                      win[(ky + dy) * WIN + (kx + dx)] * wr[ky * K + kx];
        }
      }
      #pragma unroll
      for (int j = 0; j < GOC_R; ++j) {
        const int oc = os + g * GOC_R + j;
        float m = acc[j][0];
        #pragma unroll
        for (int q = 1; q < POOL * POOL; ++q) m = fmaxf(m, acc[j][q]);
        float v = m * ab[oc] + ab[COUT + oc];
        v = fminf(fmaxf(v, -1.f), 1.f);
        out[((size_t)img * NPIX + p) * COUT + oc] = v;     // NHWC
      }
    }
  }
}

// ---------------- MFMA implicit-GEMM conv + pool2 + bn + ht ----------------
// in:  fp32 NHWC [img][IN_W*IN_W][CIN]
// wb:  bf16 [tap][COUT][CIN]  (tap = ky*KW+kx)
// out: fp32 NHWC [img][PW*PW][COUT]
// M = pooled-pixel-major conv pixels: m = pp*4 + (dy*2+dx); K = tap-major.
template <int CIN, int COUT, int KW, int PAD, int IN_W, int PW>
__global__ __launch_bounds__(256, 2) void conv_mfma(
    const float* __restrict__ in, const short* __restrict__ wb,
    const float* __restrict__ ab, float* __restrict__ out) {
  constexpr int S = CIN / 8;                  // 16B blocks per pixel (pow2)
  constexpr int CPT = CIN / 32;               // k-chunks per tap
  constexpr int NPIXIN = IN_W * IN_W;
  constexpr int PP = PW * PW;
  constexpr int M_TILES = (PP + 3) / 4;
  constexpr int NG = COUT / 64;               // n-groups of 4 n-tiles
  constexpr int NCHK = NPIXIN * S;

  __shared__ __align__(16) short simg[NPIXIN * CIN];

  const int img = blockIdx.x;
  const float* __restrict__ gin = in + (size_t)img * NPIXIN * CIN;

  // stage fp32 NHWC -> bf16 LDS, 16B blocks XOR-swizzled by pixel
  for (int c = threadIdx.x; c < NCHK; c += 256) {
    const int pix = c / S;
    const int cblk = c & (S - 1);
    const float4 f0 = *(const float4*)(gin + (size_t)c * 8);
    const float4 f1 = *(const float4*)(gin + (size_t)c * 8 + 4);
    bf16x8 v;
    v[0] = f2bf(f0.x); v[1] = f2bf(f0.y); v[2] = f2bf(f0.z); v[3] = f2bf(f0.w);
    v[4] = f2bf(f1.x); v[5] = f2bf(f1.y); v[6] = f2bf(f1.z); v[7] = f2bf(f1.w);
    *(bf16x8*)&simg[(pix * S + (cblk ^ (pix & (S - 1)))) * 8] = v;
  }
  __syncthreads();

  const int lane = threadIdx.x & 63;
  const int wv = threadIdx.x >> 6;
  const int mrow = lane & 15;                 // A-row / B-col / C-col
  const int quad = lane >> 4;

  for (int u = wv; u < M_TILES * NG; u += 4) {
    const int mt = u % M_TILES;
    const int ng = u / M_TILES;
    const int m = mt * 16 + mrow;
    const int pp = m >> 2, q = m & 3;
    const int py = pp / PW, px = pp - py * PW;
    const int y = py * 2 + (q >> 1), x = px * 2 + (q & 1);
    const bool mvalid = pp < PP;

    f32x4 acc[4];
    #pragma unroll
    for (int nt = 0; nt < 4; ++nt) acc[nt] = (f32x4){0.f, 0.f, 0.f, 0.f};

    #pragma unroll
    for (int t = 0; t < KW * KW; ++t) {
      const int iy = y + t / KW - PAD;
      const int ix = x + t % KW - PAD;
      const bool av = mvalid && ((unsigned)iy < (unsigned)IN_W) &&
                      ((unsigned)ix < (unsigned)IN_W);
      const int pin = iy * IN_W + ix;
      #pragma unroll
      for (int s = 0; s < CPT; ++s) {
        bf16x8 afrag;
        if (av) {
          afrag = *(const bf16x8*)&simg[(pin * S + ((s * 4 + quad) ^ (pin & (S - 1)))) * 8];
        } else {
          afrag = (bf16x8){0, 0, 0, 0, 0, 0, 0, 0};
        }
        #pragma unroll
        for (int nt = 0; nt < 4; ++nt) {
          const bf16x8 bfrag = *(const bf16x8*)&wb[
              ((size_t)t * COUT + ng * 64 + nt * 16 + mrow) * CIN + s * 32 + quad * 8];
          acc[nt] = __builtin_amdgcn_mfma_f32_16x16x32_bf16(afrag, bfrag, acc[nt], 0, 0, 0);
        }
      }
    }

    // lane holds pooled pixel ppo = mt*4+quad, its 4 pool candidates in regs
    const int ppo = mt * 4 + quad;
    if (ppo < PP) {
      #pragma unroll
      for (int nt = 0; nt < 4; ++nt) {
        const int oc = ng * 64 + nt * 16 + mrow;
        const float mx = fmaxf(fmaxf(acc[nt][0], acc[nt][1]),
                               fmaxf(acc[nt][2], acc[nt][3]));
        float v2 = mx * ab[oc] + ab[COUT + oc];
        v2 = fminf(fmaxf(v2, -1.f), 1.f);
        out[((size_t)img * PP + ppo) * COUT + oc] = v2;
      }
    }
  }
}

// ---------------- conv5 (1x1) as NHWC GEMM; writes NCHW-flatten order ------
__global__ __launch_bounds__(256, 2) void conv5_fc(
    const float* __restrict__ in, const float* __restrict__ w5t,
    const float* __restrict__ ab, float* __restrict__ out) {
  __shared__ float sin[9 * 256];
  const int img = blockIdx.x;
  const int oc = threadIdx.x;
  for (int i = threadIdx.x; i < 2304; i += 256)
    sin[i] = in[(size_t)img * 2304 + i];
  __syncthreads();
  float acc[9];
  #pragma unroll
  for (int p = 0; p < 9; ++p) acc[p] = 0.f;
  for (int ci = 0; ci < 256; ++ci) {
    const float wv = w5t[ci * 256 + oc];       // coalesced, L2-hot
    #pragma unroll
    for (int p = 0; p < 9; ++p) acc[p] += sin[p * 256 + ci] * wv;  // broadcast
  }
  const float A = ab[oc], Bc = ab[256 + oc];
  #pragma unroll
  for (int p = 0; p < 9; ++p) {
    float v = fminf(fmaxf(acc[p] * A + Bc, -1.f), 1.f);
    out[(size_t)img * 2304 + oc * 9 + p] = v;  // flatten order = NCHW
  }
}

// ---------------- FC gemm + bn + ht: C[M,N] = X[M,K] . W[N,K]^T ----------------
__global__ __launch_bounds__(256, 2) void fc_bn_ht(
    const float* __restrict__ X, const float* __restrict__ W,
    const float* __restrict__ ab, float* __restrict__ out,
    int M, int N, int K, int doHt) {
  __shared__ __align__(16) float Xs[16][64];
  __shared__ __align__(16) float Ws[16][64];
  const int bm = blockIdx.y * 64, bn = blockIdx.x * 64;
  const int tx = threadIdx.x & 15, ty = threadIdx.x >> 4;
  const int lr = threadIdx.x >> 2, lc = (threadIdx.x & 3) * 4;
  float acc[4][4];
  #pragma unroll
  for (int i = 0; i < 4; ++i)
    #pragma unroll
    for (int j = 0; j < 4; ++j) acc[i][j] = 0.f;
  const float* xp = X + (size_t)(bm + lr) * K + lc;
  const float* wp = W + (size_t)(bn + lr) * K + lc;
  for (int k0 = 0; k0 < K; k0 += 16) {
    const float4 xv = *(const float4*)(xp + k0);
    const float4 wv = *(const float4*)(wp + k0);
    __syncthreads();
    Xs[lc + 0][lr] = xv.x; Xs[lc + 1][lr] = xv.y;
    Xs[lc + 2][lr] = xv.z; Xs[lc + 3][lr] = xv.w;
    Ws[lc + 0][lr] = wv.x; Ws[lc + 1][lr] = wv.y;
    Ws[lc + 2][lr] = wv.z; Ws[lc + 3][lr] = wv.w;
    __syncthreads();
    #pragma unroll
    for (int kk = 0; kk < 16; ++kk) {
      const float4 a = *(const float4*)(&Xs[kk][tx * 4]);
      const float4 b = *(const float4*)(&Ws[kk][ty * 4]);
      const float av[4] = {a.x, a.y, a.z, a.w};
      const float bv[4] = {b.x, b.y, b.z, b.w};
      #pragma unroll
      for (int i = 0; i < 4; ++i)
        #pragma unroll
        for (int j = 0; j < 4; ++j) acc[i][j] += av[i] * bv[j];
    }
  }
  #pragma unroll
  for (int i = 0; i < 4; ++i) {
    const int m = bm + tx * 4 + i;
    #pragma unroll
    for (int j = 0; j < 4; ++j) {
      const int n = bn + ty * 4 + j;
      float v = acc[i][j] * ab[n] + ab[N + n];
      if (doHt) v = fminf(fmaxf(v, -1.f), 1.f);
      out[(size_t)m * N + n] = v;
    }
  }
}

// ---------------- FC3: [1024,512] x [10,512]^T + bias ----------------
__global__ __launch_bounds__(256) void fc3_kernel(
    const float* __restrict__ X, const float* __restrict__ W,
    const float* __restrict__ bias, float* __restrict__ out) {
  __shared__ float ws[512 * 10 + 16];
  for (int li = threadIdx.x; li < 5120; li += 256) {
    int n = li / 512, k = li - n * 512;
    ws[k * 10 + n] = W[li];
  }
  __syncthreads();
  const int il = threadIdx.x >> 4, n = threadIdx.x & 15;
  const int img = blockIdx.x * 16 + il;
  if (n < 10) {
    const float* xp = X + (size_t)img * 512;
    float s = 0.f;
    for (int k = 0; k < 512; ++k) s += xp[k] * ws[k * 10 + n];
    out[img * 10 + n] = s + bias[n];
  }
}

// ---------------- launch ----------------
extern "C" void kernel_launch(void* const* d_in, const int* in_sizes, int n_in,
                              void* d_out, int out_size, void* d_ws, size_t ws_size,
                              hipStream_t stream) {
  (void)in_sizes; (void)n_in; (void)out_size; (void)ws_size;
  const float* x = (const float*)d_in[0];
  float* W = (float*)d_ws;

  // persistent weight region (floats)
  float* wq1 = W + 0;                   // 800
  float* fq1 = W + 832;                 // 2359296
  float* fq2 = W + 2360128;             // 524288
  float* fq3 = W + 2884416;             // 5120
  float* ab  = W + 2889536;             // 4544
  short* wb2 = (short*)(W + 2894080);   // 51200 bf16
  short* wb3 = (short*)(W + 2919680);   // 73728 bf16
  short* wb4 = (short*)(W + 2956544);   // 294912 bf16
  float* w5t = W + 3104000;             // 65536
  // activation buffers (same footprint as round 1)
  float* bufA = W + 3379456;            // 25690112 floats
  float* bufB = W + 29069568;           // 12845056 floats

  // fp32 quant scratch lives in bufA (consumed before conv1 writes h1)
  float* qs2 = bufA + 0;                // 51200
  float* qs3 = bufA + 51200;            // 73728
  float* qs4 = bufA + 124928;           // 294912
  float* qs5 = bufA + 419840;           // 65536

  // activation slices
  float* h1 = bufA;                     // [1024][784][32]  = 25690112
  float* h2 = bufB;                     // [1024][196][64]  = 12845056
  float* h3 = bufA;                     // [1024][49][128]  = 6422528
  float* h5 = bufA + 6422528;           // [1024][2304]     = 2359296
  float* f2 = bufA + 8781824;           // [1024][512]      = 524288
  float* h4 = bufB;                     // [1024][9][256]   = 2359296
  float* f1 = bufB + 2359296;           // [1024][1024]     = 1048576

  // 1) fake-quant all weights
  QuantArgs qa;
  const int widx[8] = {1, 7, 13, 19, 25, 31, 37, 43};
  float* qdst[8] = {wq1, qs2, qs3, qs4, qs5, fq1, fq2, fq3};
  const int cik[8] = {25, 800, 576, 1152, 256, 2304, 1024, 512};
  const int co[8] = {32, 64, 128, 256, 256, 1024, 512, 10};
  int cum = 0;
  for (int i = 0; i < 8; ++i) {
    qa.w[i] = (const float*)d_in[widx[i]];
    qa.q[i] = qdst[i];
    qa.cik[i] = cik[i];
    qa.cum[i] = cum;
    cum += co[i];
  }
  qa.cum[8] = cum;
  hipLaunchKernelGGL(quant_all, dim3(cum), dim3(256), 0, stream, qa);

  // 2) repack conv2/3/4 weights to bf16 tap-major; transpose w5
  hipLaunchKernelGGL(repack_w, dim3((51200 + 255) / 256), dim3(256), 0, stream,
                     qs2, wb2, 64, 32, 25);
  hipLaunchKernelGGL(repack_w, dim3((73728 + 255) / 256), dim3(256), 0, stream,
                     qs3, wb3, 128, 64, 9);
  hipLaunchKernelGGL(repack_w, dim3((294912 + 255) / 256), dim3(256), 0, stream,
                     qs4, wb4, 256, 128, 9);
  hipLaunchKernelGGL(transpose_w5, dim3(256), dim3(256), 0, stream, qs5, w5t);

  // 3) fold BN params
  BnArgs ba;
  const int bbase[7] = {2, 8, 14, 20, 26, 32, 38};
  const int bc[7] = {32, 64, 128, 256, 256, 1024, 512};
  const int abo[7] = {0, 64, 192, 448, 960, 1472, 3520};
  int bcum = 0;
  for (int t = 0; t < 7; ++t) {
    for (int j = 0; j < 5; ++j) ba.p[t][j] = (const float*)d_in[bbase[t] + j];
    ba.C[t] = bc[t];
    ba.abo[t] = abo[t];
    ba.cum[t] = bcum;
    bcum += bc[t];
  }
  ba.cum[7] = bcum;
  ba.ab = ab;
  hipLaunchKernelGGL(bn_all, dim3((bcum + 255) / 256), dim3(256), 0, stream, ba);

  // 4) conv stack
  hipLaunchKernelGGL((conv_bn_ht_A<1, 32, 5, 2, 28, 1, 32, 4>), dim3(1024), dim3(256), 0, stream,
                     x, wq1, ab + 0, h1);                        // NHWC [B,784,32]
  hipLaunchKernelGGL((conv_mfma<32, 64, 5, 2, 28, 14>), dim3(1024), dim3(256), 0, stream,
                     h1, wb2, ab + 64, h2);                      // [B,196,64]
  hipLaunchKernelGGL((conv_mfma<64, 128, 3, 1, 14, 7>), dim3(1024), dim3(256), 0, stream,
                     h2, wb3, ab + 192, h3);                     // [B,49,128]
  hipLaunchKernelGGL((conv_mfma<128, 256, 3, 1, 7, 3>), dim3(1024), dim3(256), 0, stream,
                     h3, wb4, ab + 448, h4);                     // [B,9,256]
  hipLaunchKernelGGL(conv5_fc, dim3(1024), dim3(256), 0, stream,
                     h4, w5t, ab + 960, h5);                     // [B,2304] flatten order

  // 5) FC stack
  hipLaunchKernelGGL(fc_bn_ht, dim3(1024 / 64, 1024 / 64), dim3(256), 0, stream,
                     h5, fq1, ab + 1472, f1, 1024, 1024, 2304, 1);
  hipLaunchKernelGGL(fc_bn_ht, dim3(512 / 64, 1024 / 64), dim3(256), 0, stream,
                     f1, fq2, ab + 3520, f2, 1024, 512, 1024, 1);
  hipLaunchKernelGGL(fc3_kernel, dim3(64), dim3(256), 0, stream,
                     f2, fq3, (const float*)d_in[44], (float*)d_out);
}

// Round 3
// 534.733 us; speedup vs baseline: 9.3032x; 2.6194x over previous
//
#include <hip/hip_runtime.h>
#include <hip/hip_bf16.h>
#include <math.h>

// ---------------------------------------------------------------------------
// BinaryCNN round 3:
//  - conv1/2/3/4 + fc1 on bf16 MFMA (16x16x32) with EXACT-INT weights
//    (per-channel quant scale folded into BN A => zero weight-rounding error)
//  - weights pre-repacked into MFMA fragment order -> LDS staging is a linear
//    int4 copy and B-frag ds_reads are conflict-free by construction
//  - conv2/3: chunk-resident weights in LDS, m-outer K-inner, pool in-register
//  - conv4: tap-outer, double-buffered per-tap weights, acc-resident output
//  - fc1: X in hi/lo bf16 split (written by conv5 in fragment order)
//  - conv5/fc2/fc3 stay fp32 VALU (accuracy anchors)
// ---------------------------------------------------------------------------

#define EPS 1e-5f

typedef __attribute__((ext_vector_type(8))) short bf16x8;
typedef __attribute__((ext_vector_type(4))) float f32x4;
typedef __attribute__((ext_vector_type(4))) int i32x4;

__device__ __forceinline__ short f2bf(float f) {
  unsigned u = __builtin_bit_cast(unsigned, f);
  unsigned r = u + 0x7FFFu + ((u >> 16) & 1u);   // RNE
  return (short)(r >> 16);
}
__device__ __forceinline__ float bf2f(short h) {
  unsigned u = ((unsigned)(unsigned short)h) << 16;
  return __builtin_bit_cast(float, u);
}

// ---------------- weight fake-quant: per-output-channel scale + dequant -----
struct QuantArgs {
  const float* w[8];
  float* q[8];     // dequantized fp32 (only used for conv5/fc2/fc3)
  float* sc[8];    // per-channel scale out
  int cik[8];
  int cum[9];
};

__global__ __launch_bounds__(256) void quant_all(QuantArgs a) {
  int b = blockIdx.x;
  int t = 0;
  while (b >= a.cum[t + 1]) t++;
  int co = b - a.cum[t];
  int cik = a.cik[t];
  const float* src = a.w[t] + (size_t)co * cik;
  float* dst = a.q[t] + (size_t)co * cik;
  float m = 0.f;
  for (int i = threadIdx.x; i < cik; i += 256) m = fmaxf(m, fabsf(src[i]));
  #pragma unroll
  for (int o = 1; o < 64; o <<= 1) m = fmaxf(m, __shfl_xor(m, o));
  __shared__ float red[4];
  __shared__ float ssh;
  if ((threadIdx.x & 63) == 0) red[threadIdx.x >> 6] = m;
  __syncthreads();
  if (threadIdx.x == 0) {
    m = fmaxf(fmaxf(red[0], red[1]), fmaxf(red[2], red[3]));
    float s = fmaxf(m / 127.0f, 1e-8f);
    ssh = s;
    a.sc[t][co] = s;
  }
  __syncthreads();
  float s = ssh;
  for (int i = threadIdx.x; i < cik; i += 256) {
    float q = rintf(src[i] / s);               // RNE, like jnp.round
    q = fminf(fmaxf(q, -128.f), 127.f);
    dst[i] = q * s;
  }
}

// ---------------- conv1 weights -> int-bf16 frag order [nt][q][mr][j] -------
__global__ __launch_bounds__(256) void repack_c1(const float* __restrict__ w,
                                                 const float* __restrict__ sc,
                                                 short* __restrict__ dst) {
  int i = blockIdx.x * 256 + threadIdx.x;      // 32 oc x 32 taps
  if (i >= 1024) return;
  int oc = i >> 5, t = i & 31;
  float v = 0.f;
  if (t < 25) {
    float s = sc[oc];
    v = fminf(fmaxf(rintf(w[oc * 25 + t] / s), -128.f), 127.f);
  }
  dst[(((oc >> 4) * 4 + (t >> 3)) * 16 + (oc & 15)) * 8 + (t & 7)] = f2bf(v);
}

// ---- conv2/3/4 weights -> int-bf16 frag order [chunk][kk][nt][ks][q][mr][j] --
__global__ __launch_bounds__(256) void repack_frag(const float* __restrict__ w,
                                                   const float* __restrict__ sc,
                                                   short* __restrict__ dst,
                                                   int CO, int CI, int KK, int OCCH) {
  int i = blockIdx.x * 256 + threadIdx.x;
  int total = CO * CI * KK;
  if (i >= total) return;
  int oc = i / (CI * KK);
  int r = i - oc * (CI * KK);
  int ci = r / KK;
  int kk = r - ci * KK;
  float s = sc[oc];
  float q = fminf(fmaxf(rintf(w[i] / s), -128.f), 127.f);
  int NTC = OCCH >> 4;
  int KS = CI >> 5; if (KS == 0) KS = 1;
  int chunk = oc / OCCH;
  int ocl = oc - chunk * OCCH;
  int ntl = ocl >> 4, mr = ocl & 15;
  int ks = ci >> 5, qq = (ci >> 3) & 3, j = ci & 7;
  size_t d = ((((((size_t)(chunk * KK + kk) * NTC + ntl) * KS + ks) * 4 + qq) * 16 + mr)) * 8 + j;
  dst[d] = f2bf(q);
}

// ---- fc1 weights -> int-bf16 block-frag order [nblk][kc][nt][ks][q][mr][j] --
__global__ __launch_bounds__(256) void repack_fc1(const float* __restrict__ w,
                                                  const float* __restrict__ sc,
                                                  short* __restrict__ dst) {
  int i = blockIdx.x * 256 + threadIdx.x;      // 1024 x 2304
  if (i >= 1024 * 2304) return;
  int n = i / 2304, k = i - n * 2304;
  float s = sc[n];
  float q = fminf(fmaxf(rintf(w[i] / s), -128.f), 127.f);
  int nblk = n >> 6, ntl = (n >> 4) & 3, mr = n & 15;
  int kc = k >> 7, ks = (k >> 5) & 3, qq = (k >> 3) & 3, j = k & 7;
  size_t d = (((((((size_t)nblk * 18 + kc) * 4 + ntl) * 4 + ks) * 4 + qq) * 16 + mr)) * 8 + j;
  dst[d] = f2bf(q);
}

// ---------------- transpose w5: [oc][ci] -> [ci][oc] (fp32) ----------------
__global__ __launch_bounds__(256) void transpose_w5(const float* __restrict__ src,
                                                    float* __restrict__ dst) {
  int i = blockIdx.x * 256 + threadIdx.x;    // 65536
  int oc = i >> 8, ci = i & 255;
  dst[ci * 256 + oc] = src[i];
}

// ------ fold BN (+conv bias, + int-weight scale) into per-channel A,B ------
struct BnArgs {
  const float* p[7][5];   // b, g, be, mu, va
  const float* wsc;
  float* ab;
  int C[7];
  int abo[7];
  int sco[7];
  int us[7];
  int cum[8];
};

__global__ __launch_bounds__(256) void bn_all(BnArgs a) {
  int i = blockIdx.x * 256 + threadIdx.x;
  if (i >= a.cum[7]) return;
  int t = 0;
  while (i >= a.cum[t + 1]) t++;
  int c = i - a.cum[t];
  float A = a.p[t][1][c] / sqrtf(a.p[t][4][c] + EPS);
  float B = (a.p[t][0][c] - a.p[t][3][c]) * A + a.p[t][2][c];
  float As = a.us[t] ? A * a.wsc[a.sco[t] + c] : A;
  a.ab[a.abo[t] + c] = As;
  a.ab[a.abo[t] + a.C[t] + c] = B;
}

// ---------------- conv1: MFMA via im2col in LDS (K=32, taps padded) --------
__global__ __launch_bounds__(448, 2) void conv1_mfma(
    const float* __restrict__ x, const short* __restrict__ wb1,
    const float* __restrict__ ab, short* __restrict__ out) {
  __shared__ __align__(16) float sx[784];
  __shared__ __align__(16) short sim[784 * 32];
  __shared__ __align__(16) short sw1[1024];
  const int tid = threadIdx.x;
  const int img = blockIdx.x;
  for (int i = tid; i < 784; i += 448) sx[i] = x[(size_t)img * 784 + i];
  for (int i = tid; i < 1024; i += 448) sw1[i] = wb1[i];
  __syncthreads();
  for (int i = tid; i < 25088; i += 448) {
    int p = i >> 5, t = i & 31;
    short v = 0;
    if (t < 25) {
      int py = p / 28, px = p - py * 28;
      int iy = py + t / 5 - 2, ix = px + t % 5 - 2;
      if ((unsigned)iy < 28u && (unsigned)ix < 28u) v = f2bf(sx[iy * 28 + ix]);
    }
    sim[i] = v;
  }
  __syncthreads();
  const int lane = tid & 63, wv = tid >> 6;
  const int mrow = lane & 15, quad = lane >> 4;
  f32x4 acc[7][2];
  #pragma unroll
  for (int i = 0; i < 7; ++i) {
    acc[i][0] = (f32x4){0.f, 0.f, 0.f, 0.f};
    acc[i][1] = (f32x4){0.f, 0.f, 0.f, 0.f};
  }
  #pragma unroll
  for (int i = 0; i < 7; ++i) {
    const int mt = wv * 7 + i;
    const bf16x8 a = *(const bf16x8*)&sim[(mt * 16 + mrow) * 32 + quad * 8];
    #pragma unroll
    for (int nt = 0; nt < 2; ++nt) {
      const bf16x8 b = *(const bf16x8*)&sw1[(nt * 4 + quad) * 128 + mrow * 8];
      acc[i][nt] = __builtin_amdgcn_mfma_f32_16x16x32_bf16(a, b, acc[i][nt], 0, 0, 0);
    }
  }
  #pragma unroll
  for (int i = 0; i < 7; ++i) {
    const int mt = wv * 7 + i;
    #pragma unroll
    for (int nt = 0; nt < 2; ++nt) {
      const int oc = nt * 16 + mrow;
      const float A = ab[oc], Bc = ab[32 + oc];
      #pragma unroll
      for (int r = 0; r < 4; ++r) {
        const int p = mt * 16 + quad * 4 + r;
        float v = fminf(fmaxf(acc[i][nt][r] * A + Bc, -1.f), 1.f);
        out[((size_t)img * 784 + p) * 32 + oc] = f2bf(v);
      }
    }
  }
}

// -------- conv2/conv3: chunk-resident weights, m-outer, pool in-register ----
// in: bf16 NHWC; wfrag: frag order; out: bf16 NHWC pooled
template <int CIN, int COUT, int KW, int PAD, int IN_W, int PW, int IMGS,
          int MTPI, int MTW, int OCCH>
__global__ __launch_bounds__(448, 2) void conv23_mfma(
    const short* __restrict__ in, const short* __restrict__ wfrag,
    const float* __restrict__ ab, short* __restrict__ out) {
  constexpr int S = CIN / 8;
  constexpr int NPIX = IN_W * IN_W;
  constexpr int PP = PW * PW;
  constexpr int KS = CIN / 32;
  constexpr int NTC = OCCH / 16;
  constexpr int KK = KW * KW;
  constexpr int CHUNKS = COUT / OCCH;
  constexpr int WCH = KK * NTC * KS * 512;   // shorts per chunk
  constexpr int INCH = IMGS * NPIX * S;      // 16B input units
  __shared__ __align__(16) short simg[IMGS * NPIX * CIN];
  __shared__ __align__(16) short sw[WCH];

  const int tid = threadIdx.x;
  const int img0 = blockIdx.x * IMGS;
  const int lane = tid & 63, wv = tid >> 6;
  const int mrow = lane & 15, quad = lane >> 4;

  int yy[MTW], xx[MTW], ibs[MTW], ppo_[MTW], ilv[MTW];
  bool rv[MTW], pv[MTW];
  #pragma unroll
  for (int i = 0; i < MTW; ++i) {
    int mt = wv * MTW + i;
    bool tv = mt < IMGS * MTPI;
    int il = mt / MTPI; if (il >= IMGS) il = IMGS - 1;
    int lt = mt - il * MTPI;
    int m = lt * 16 + mrow;
    int pp = m >> 2, cd = m & 3;
    rv[i] = tv && (pp < PP);
    int py = pp / PW, px = pp - py * PW;
    yy[i] = py * 2 + (cd >> 1);
    xx[i] = px * 2 + (cd & 1);
    ibs[i] = il * (NPIX * S);
    ilv[i] = il;
    ppo_[i] = lt * 4 + quad;
    pv[i] = tv && (ppo_[i] < PP);
  }

  f32x4 acc[MTW][NTC];
  for (int ch = 0; ch < CHUNKS; ++ch) {
    if (ch == 0) {
      const i32x4* gsrc = (const i32x4*)(in + (size_t)img0 * NPIX * CIN);
      for (int c = tid; c < INCH; c += 448) {
        int il = c / (NPIX * S);
        int r = c - il * (NPIX * S);
        int pix = r >> (S == 4 ? 2 : 3);
        int blk = r & (S - 1);
        ((i32x4*)simg)[il * (NPIX * S) + pix * S + (blk ^ (pix & (S - 1)))] = gsrc[c];
      }
    }
    {
      const i32x4* wsrc = (const i32x4*)(wfrag + (size_t)ch * WCH);
      for (int u = tid; u < WCH / 8; u += 448) ((i32x4*)sw)[u] = wsrc[u];
    }
    __syncthreads();

    #pragma unroll
    for (int i = 0; i < MTW; ++i)
      #pragma unroll
      for (int nt = 0; nt < NTC; ++nt) acc[i][nt] = (f32x4){0.f, 0.f, 0.f, 0.f};

    int dy = -PAD, dx = -PAD;
    for (int t = 0; t < KK; ++t) {
      #pragma unroll
      for (int ks = 0; ks < KS; ++ks) {
        bf16x8 af[MTW];
        #pragma unroll
        for (int i = 0; i < MTW; ++i) {
          int iy = yy[i] + dy, ix = xx[i] + dx;
          bool ok = rv[i] && ((unsigned)iy < (unsigned)IN_W) && ((unsigned)ix < (unsigned)IN_W);
          int pin = iy * IN_W + ix;
          int blk = (ks * 4 + quad) ^ (pin & (S - 1));
          af[i] = ok ? *(const bf16x8*)&simg[(ibs[i] + pin * S + blk) * 8]
                     : (bf16x8){0, 0, 0, 0, 0, 0, 0, 0};
        }
        #pragma unroll
        for (int nt = 0; nt < NTC; ++nt) {
          const bf16x8 bf = *(const bf16x8*)&sw[(((t * NTC + nt) * KS + ks) * 4 + quad) * 128 + mrow * 8];
          #pragma unroll
          for (int i = 0; i < MTW; ++i)
            acc[i][nt] = __builtin_amdgcn_mfma_f32_16x16x32_bf16(af[i], bf, acc[i][nt], 0, 0, 0);
        }
      }
      dx++;
      if (dx == KW - PAD) { dx = -PAD; dy++; }
    }
    __syncthreads();

    #pragma unroll
    for (int i = 0; i < MTW; ++i) {
      if (pv[i]) {
        #pragma unroll
        for (int nt = 0; nt < NTC; ++nt) {
          const int oc = ch * OCCH + nt * 16 + mrow;
          float mx = fmaxf(fmaxf(acc[i][nt][0], acc[i][nt][1]),
                           fmaxf(acc[i][nt][2], acc[i][nt][3]));
          float v = fminf(fmaxf(mx * ab[oc] + ab[COUT + oc], -1.f), 1.f);
          out[((size_t)(img0 + ilv[i]) * PP + ppo_[i]) * COUT + oc] = f2bf(v);
        }
      }
    }
  }
}

// -------- conv4: tap-outer, double-buffered tap weights, fp32 NHWC out ------
__global__ __launch_bounds__(512, 2) void conv4_mfma(
    const short* __restrict__ in,      // h3 bf16 [img][49][128]
    const short* __restrict__ wfrag,   // [9][16][4][4][16][8]
    const float* __restrict__ ab, float* __restrict__ out) {
  constexpr int S = 16, NPIX = 49, PP = 9;
  __shared__ __align__(16) short simg[2 * NPIX * 128];
  __shared__ __align__(16) short swb[2][32768];
  const int tid = threadIdx.x;
  const int img0 = blockIdx.x * 2;
  const int lane = tid & 63, wv = tid >> 6;
  const int mrow = lane & 15, quad = lane >> 4;

  {
    const i32x4* gsrc = (const i32x4*)(in + (size_t)img0 * NPIX * 128);
    for (int c = tid; c < 2 * NPIX * S; c += 512) {
      int il = c / (NPIX * S);
      int r = c - il * (NPIX * S);
      int pix = r >> 4, blk = r & 15;
      ((i32x4*)simg)[il * NPIX * S + pix * S + (blk ^ (pix & 15))] = gsrc[c];
    }
    for (int u = tid; u < 4096; u += 512)
      ((i32x4*)swb[0])[u] = ((const i32x4*)wfrag)[u];
  }

  int yy[6], xx[6], ibs[6], ppo_[6], ilv[6];
  bool rv[6], pv[6];
  #pragma unroll
  for (int i = 0; i < 6; ++i) {
    int il = i / 3, lt = i - il * 3;
    int m = lt * 16 + mrow;
    int pp = m >> 2, cd = m & 3;
    rv[i] = pp < PP;
    int py = pp / 3, px = pp - py * 3;
    yy[i] = py * 2 + (cd >> 1);
    xx[i] = px * 2 + (cd & 1);
    ibs[i] = il * NPIX * S;
    ilv[i] = il;
    ppo_[i] = lt * 4 + quad;
    pv[i] = ppo_[i] < PP;
  }
  const int nt0 = wv, nt1 = wv + 8;
  f32x4 acc[6][2];
  #pragma unroll
  for (int i = 0; i < 6; ++i) {
    acc[i][0] = (f32x4){0.f, 0.f, 0.f, 0.f};
    acc[i][1] = (f32x4){0.f, 0.f, 0.f, 0.f};
  }
  __syncthreads();

  int dy = -1, dx = -1;
  for (int t = 0; t < 9; ++t) {
    const int buf = t & 1;
    if (t < 8) {
      const i32x4* wsrc = (const i32x4*)(wfrag + (size_t)(t + 1) * 32768);
      for (int u = tid; u < 4096; u += 512) ((i32x4*)swb[buf ^ 1])[u] = wsrc[u];
    }
    #pragma unroll
    for (int ks = 0; ks < 4; ++ks) {
      bf16x8 af[6];
      #pragma unroll
      for (int i = 0; i < 6; ++i) {
        int iy = yy[i] + dy, ix = xx[i] + dx;
        bool ok = rv[i] && (unsigned)iy < 7u && (unsigned)ix < 7u;
        int pin = iy * 7 + ix;
        int blk = (ks * 4 + quad) ^ (pin & 15);
        af[i] = ok ? *(const bf16x8*)&simg[(ibs[i] + pin * S + blk) * 8]
                   : (bf16x8){0, 0, 0, 0, 0, 0, 0, 0};
      }
      const bf16x8 b0 = *(const bf16x8*)&swb[buf][((nt0 * 4 + ks) * 4 + quad) * 128 + mrow * 8];
      const bf16x8 b1 = *(const bf16x8*)&swb[buf][((nt1 * 4 + ks) * 4 + quad) * 128 + mrow * 8];
      #pragma unroll
      for (int i = 0; i < 6; ++i) {
        acc[i][0] = __builtin_amdgcn_mfma_f32_16x16x32_bf16(af[i], b0, acc[i][0], 0, 0, 0);
        acc[i][1] = __builtin_amdgcn_mfma_f32_16x16x32_bf16(af[i], b1, acc[i][1], 0, 0, 0);
      }
    }
    dx++;
    if (dx == 2) { dx = -1; dy++; }
    __syncthreads();
  }

  #pragma unroll
  for (int i = 0; i < 6; ++i) {
    if (pv[i]) {
      #pragma unroll
      for (int nj = 0; nj < 2; ++nj) {
        const int oc = (nj ? nt1 : nt0) * 16 + mrow;
        const f32x4 a = acc[i][nj];
        float mx = fmaxf(fmaxf(a[0], a[1]), fmaxf(a[2], a[3]));
        float v = fminf(fmaxf(mx * ab[oc] + ab[256 + oc], -1.f), 1.f);
        out[((size_t)(img0 + ilv[i]) * PP + ppo_[i]) * 256 + oc] = v;
      }
    }
  }
}

// ------ conv5 (1x1) fp32 VALU; writes h5 hi/lo bf16 in fc1 frag order -------
__global__ __launch_bounds__(256, 2) void conv5_fc(
    const float* __restrict__ in, const float* __restrict__ w5t,
    const float* __restrict__ ab, short* __restrict__ oh, short* __restrict__ ol) {
  __shared__ float sin[9 * 256];
  const int img = blockIdx.x;
  const int oc = threadIdx.x;
  for (int i = threadIdx.x; i < 2304; i += 256)
    sin[i] = in[(size_t)img * 2304 + i];
  __syncthreads();
  float acc[9];
  #pragma unroll
  for (int p = 0; p < 9; ++p) acc[p] = 0.f;
  for (int ci = 0; ci < 256; ++ci) {
    const float wv = w5t[ci * 256 + oc];
    #pragma unroll
    for (int p = 0; p < 9; ++p) acc[p] += sin[p * 256 + ci] * wv;
  }
  const float A = ab[oc], Bc = ab[256 + oc];
  const int mblk = img >> 6, mtq = (img >> 4) & 3, mr = img & 15;
  #pragma unroll
  for (int p = 0; p < 9; ++p) {
    float v = fminf(fmaxf(acc[p] * A + Bc, -1.f), 1.f);
    int k = oc * 9 + p;
    int kc = k >> 7, ks = (k >> 5) & 3, qq = (k >> 3) & 3, j = k & 7;
    size_t d = (((((((size_t)mblk * 18 + kc) * 4 + mtq) * 4 + ks) * 4 + qq) * 16 + mr)) * 8 + j;
    short hi = f2bf(v);
    oh[d] = hi;
    ol[d] = f2bf(v - bf2f(hi));
  }
}

// ---------------- fc1: MFMA GEMM, X hi/lo, int-bf16 W, bn+ht ----------------
__global__ __launch_bounds__(256, 2) void fc1_mfma(
    const short* __restrict__ Xh, const short* __restrict__ Xl,
    const short* __restrict__ Wf, const float* __restrict__ ab,
    float* __restrict__ out) {
  __shared__ __align__(16) short sxh[8192];
  __shared__ __align__(16) short sxl[8192];
  __shared__ __align__(16) short swt[8192];
  const int tid = threadIdx.x;
  const int bn = blockIdx.x, bm = blockIdx.y;
  const int lane = tid & 63, wv = tid >> 6;
  const int mrow = lane & 15, quad = lane >> 4;
  f32x4 acc[4];
  #pragma unroll
  for (int nt = 0; nt < 4; ++nt) acc[nt] = (f32x4){0.f, 0.f, 0.f, 0.f};
  for (int kc = 0; kc < 18; ++kc) {
    __syncthreads();
    {
      const size_t xo = ((size_t)bm * 18 + kc) * 8192;
      const size_t wo = ((size_t)bn * 18 + kc) * 8192;
      #pragma unroll
      for (int u = 0; u < 4; ++u) {
        ((i32x4*)sxh)[tid + u * 256] = ((const i32x4*)(Xh + xo))[tid + u * 256];
        ((i32x4*)sxl)[tid + u * 256] = ((const i32x4*)(Xl + xo))[tid + u * 256];
        ((i32x4*)swt)[tid + u * 256] = ((const i32x4*)(Wf + wo))[tid + u * 256];
      }
    }
    __syncthreads();
    #pragma unroll
    for (int ks = 0; ks < 4; ++ks) {
      const int ao = (((wv * 4 + ks) * 4 + quad) * 16 + mrow) * 8;
      const bf16x8 ah = *(const bf16x8*)&sxh[ao];
      const bf16x8 al = *(const bf16x8*)&sxl[ao];
      #pragma unroll
      for (int nt = 0; nt < 4; ++nt) {
        const bf16x8 b = *(const bf16x8*)&swt[(((nt * 4 + ks) * 4 + quad) * 16 + mrow) * 8];
        acc[nt] = __builtin_amdgcn_mfma_f32_16x16x32_bf16(ah, b, acc[nt], 0, 0, 0);
        acc[nt] = __builtin_amdgcn_mfma_f32_16x16x32_bf16(al, b, acc[nt], 0, 0, 0);
      }
    }
  }
  #pragma unroll
  for (int nt = 0; nt < 4; ++nt) {
    const int n = bn * 64 + nt * 16 + mrow;
    const float A = ab[n], Bc = ab[1024 + n];
    #pragma unroll
    for (int r = 0; r < 4; ++r) {
      const int m = bm * 64 + wv * 16 + quad * 4 + r;
      float v = fminf(fmaxf(acc[nt][r] * A + Bc, -1.f), 1.f);
      out[(size_t)m * 1024 + n] = v;
    }
  }
}

// ---------------- FC gemm + bn + ht (fp32): C = X . W^T ----------------
__global__ __launch_bounds__(256, 2) void fc_bn_ht(
    const float* __restrict__ X, const float* __restrict__ W,
    const float* __restrict__ ab, float* __restrict__ out,
    int M, int N, int K, int doHt) {
  __shared__ __align__(16) float Xs[16][64];
  __shared__ __align__(16) float Ws[16][64];
  const int bm = blockIdx.y * 64, bn = blockIdx.x * 64;
  const int tx = threadIdx.x & 15, ty = threadIdx.x >> 4;
  const int lr = threadIdx.x >> 2, lc = (threadIdx.x & 3) * 4;
  float acc[4][4];
  #pragma unroll
  for (int i = 0; i < 4; ++i)
    #pragma unroll
    for (int j = 0; j < 4; ++j) acc[i][j] = 0.f;
  const float* xp = X + (size_t)(bm + lr) * K + lc;
  const float* wp = W + (size_t)(bn + lr) * K + lc;
  for (int k0 = 0; k0 < K; k0 += 16) {
    const float4 xv = *(const float4*)(xp + k0);
    const float4 wv = *(const float4*)(wp + k0);
    __syncthreads();
    Xs[lc + 0][lr] = xv.x; Xs[lc + 1][lr] = xv.y;
    Xs[lc + 2][lr] = xv.z; Xs[lc + 3][lr] = xv.w;
    Ws[lc + 0][lr] = wv.x; Ws[lc + 1][lr] = wv.y;
    Ws[lc + 2][lr] = wv.z; Ws[lc + 3][lr] = wv.w;
    __syncthreads();
    #pragma unroll
    for (int kk = 0; kk < 16; ++kk) {
      const float4 a = *(const float4*)(&Xs[kk][tx * 4]);
      const float4 b = *(const float4*)(&Ws[kk][ty * 4]);
      const float av[4] = {a.x, a.y, a.z, a.w};
      const float bv[4] = {b.x, b.y, b.z, b.w};
      #pragma unroll
      for (int i = 0; i < 4; ++i)
        #pragma unroll
        for (int j = 0; j < 4; ++j) acc[i][j] += av[i] * bv[j];
    }
  }
  #pragma unroll
  for (int i = 0; i < 4; ++i) {
    const int m = bm + tx * 4 + i;
    #pragma unroll
    for (int j = 0; j < 4; ++j) {
      const int n = bn + ty * 4 + j;
      float v = acc[i][j] * ab[n] + ab[N + n];
      if (doHt) v = fminf(fmaxf(v, -1.f), 1.f);
      out[(size_t)m * N + n] = v;
    }
  }
}

// ---------------- FC3 ----------------
__global__ __launch_bounds__(256) void fc3_kernel(
    const float* __restrict__ X, const float* __restrict__ W,
    const float* __restrict__ bias, float* __restrict__ out) {
  __shared__ float ws[512 * 10 + 16];
  for (int li = threadIdx.x; li < 5120; li += 256) {
    int n = li / 512, k = li - n * 512;
    ws[k * 10 + n] = W[li];
  }
  __syncthreads();
  const int il = threadIdx.x >> 4, n = threadIdx.x & 15;
  const int img = blockIdx.x * 16 + il;
  if (n < 10) {
    const float* xp = X + (size_t)img * 512;
    float s = 0.f;
    for (int k = 0; k < 512; ++k) s += xp[k] * ws[k * 10 + n];
    out[img * 10 + n] = s + bias[n];
  }
}

// ---------------- launch ----------------
extern "C" void kernel_launch(void* const* d_in, const int* in_sizes, int n_in,
                              void* d_out, int out_size, void* d_ws, size_t ws_size,
                              hipStream_t stream) {
  (void)in_sizes; (void)n_in; (void)out_size; (void)ws_size;
  const float* x = (const float*)d_in[0];
  float* W = (float*)d_ws;

  // workspace layout (floats, 64-aligned)
  float* wsc  = W + 0;          // 2304  (per-channel scales, 8 tensors)
  float* ab   = W + 2304;       // 4544 -> 6912
  float* qs5  = W + 6912;       // 65536
  float* fq2  = W + 72448;      // 524288
  float* fq3  = W + 596736;     // 5120
  short* wb1  = (short*)(W + 601856);   // 1024 sh
  short* wb2  = (short*)(W + 602368);   // 51200 sh
  short* wb3  = (short*)(W + 627968);   // 73728 sh
  short* wb4  = (short*)(W + 664832);   // 294912 sh
  float* w5t  = W + 812288;     // 65536
  short* fqb1 = (short*)(W + 877824);   // 2359296 sh
  float* qdmp = W + 2057472;    // 2359296 (dequant dump)
  short* h1   = (short*)(W + 4416768);  // [1024][784][32] bf16
  short* h2   = (short*)(W + 17261824); // [1024][196][64] bf16
  short* h3   = (short*)(W + 23684352); // [1024][49][128] bf16
  float* h4   = W + 26895616;   // [1024][2304] fp32
  short* h5h  = (short*)(W + 29254912); // frag order bf16 hi
  short* h5l  = (short*)(W + 30434560); // frag order bf16 lo
  float* f1   = W + 31614208;   // [1024][1024]
  float* f2   = W + 32662784;   // [1024][512]

  // 1) fake-quant: scales for all, dequant for conv5/fc2/fc3
  QuantArgs qa;
  const int widx[8] = {1, 7, 13, 19, 25, 31, 37, 43};
  float* qdst[8] = {qdmp, qdmp, qdmp, qdmp, qs5, qdmp, fq2, fq3};
  const int sco8[8] = {0, 32, 96, 224, 480, 736, 1760, 2272};
  const int cik[8] = {25, 800, 576, 1152, 256, 2304, 1024, 512};
  const int co[8] = {32, 64, 128, 256, 256, 1024, 512, 10};
  int cum = 0;
  for (int i = 0; i < 8; ++i) {
    qa.w[i] = (const float*)d_in[widx[i]];
    qa.q[i] = qdst[i];
    qa.sc[i] = wsc + sco8[i];
    qa.cik[i] = cik[i];
    qa.cum[i] = cum;
    cum += co[i];
  }
  qa.cum[8] = cum;
  hipLaunchKernelGGL(quant_all, dim3(cum), dim3(256), 0, stream, qa);

  // 2) repack int-bf16 frag-order weights
  hipLaunchKernelGGL(repack_c1, dim3(4), dim3(256), 0, stream,
                     (const float*)d_in[1], wsc + 0, wb1);
  hipLaunchKernelGGL(repack_frag, dim3(200), dim3(256), 0, stream,
                     (const float*)d_in[7], wsc + 32, wb2, 64, 32, 25, 64);
  hipLaunchKernelGGL(repack_frag, dim3(288), dim3(256), 0, stream,
                     (const float*)d_in[13], wsc + 96, wb3, 128, 64, 9, 64);
  hipLaunchKernelGGL(repack_frag, dim3(1152), dim3(256), 0, stream,
                     (const float*)d_in[19], wsc + 224, wb4, 256, 128, 9, 256);
  hipLaunchKernelGGL(repack_fc1, dim3(9216), dim3(256), 0, stream,
                     (const float*)d_in[31], wsc + 736, fqb1);
  hipLaunchKernelGGL(transpose_w5, dim3(256), dim3(256), 0, stream, qs5, w5t);

  // 3) fold BN (+ int-weight scale for conv1-4, fc1)
  BnArgs ba;
  const int bbase[7] = {2, 8, 14, 20, 26, 32, 38};
  const int bc[7] = {32, 64, 128, 256, 256, 1024, 512};
  const int abo[7] = {0, 64, 192, 448, 960, 1472, 3520};
  const int us7[7] = {1, 1, 1, 1, 0, 1, 0};
  int bcum = 0;
  for (int t = 0; t < 7; ++t) {
    for (int j = 0; j < 5; ++j) ba.p[t][j] = (const float*)d_in[bbase[t] + j];
    ba.C[t] = bc[t];
    ba.abo[t] = abo[t];
    ba.sco[t] = sco8[t];
    ba.us[t] = us7[t];
    ba.cum[t] = bcum;
    bcum += bc[t];
  }
  ba.cum[7] = bcum;
  ba.ab = ab;
  ba.wsc = wsc;
  hipLaunchKernelGGL(bn_all, dim3((bcum + 255) / 256), dim3(256), 0, stream, ba);

  // 4) conv stack
  hipLaunchKernelGGL(conv1_mfma, dim3(1024), dim3(448), 0, stream,
                     x, wb1, ab + 0, h1);
  hipLaunchKernelGGL((conv23_mfma<32, 64, 5, 2, 28, 14, 1, 49, 7, 64>),
                     dim3(1024), dim3(448), 0, stream, h1, wb2, ab + 64, h2);
  hipLaunchKernelGGL((conv23_mfma<64, 128, 3, 1, 14, 7, 2, 13, 4, 64>),
                     dim3(512), dim3(448), 0, stream, h2, wb3, ab + 192, h3);
  hipLaunchKernelGGL(conv4_mfma, dim3(512), dim3(512), 0, stream,
                     h3, wb4, ab + 448, h4);
  hipLaunchKernelGGL(conv5_fc, dim3(1024), dim3(256), 0, stream,
                     h4, w5t, ab + 960, h5h, h5l);

  // 5) FC stack
  hipLaunchKernelGGL(fc1_mfma, dim3(16, 16), dim3(256), 0, stream,
                     h5h, h5l, fqb1, ab + 1472, f1);
  hipLaunchKernelGGL(fc_bn_ht, dim3(8, 16), dim3(256), 0, stream,
                     f1, fq2, ab + 3520, f2, 1024, 512, 1024, 1);
  hipLaunchKernelGGL(fc3_kernel, dim3(64), dim3(256), 0, stream,
                     f2, fq3, (const float*)d_in[44], (float*)d_out);
}

// Round 4
// 475.313 us; speedup vs baseline: 10.4663x; 1.1250x over previous
//
#include <hip/hip_runtime.h>
#include <hip/hip_bf16.h>
#include <math.h>

// ---------------------------------------------------------------------------
// BinaryCNN round 4:
//  - conv2/conv3 -> 32x32x16 MFMA (2x FLOP/inst), tap-group weight chunking
//    (LDS <= 80KB -> 2 blocks/CU), uniform bank-quad LDS hash
//  - fc2 -> MFMA hi/lo (fc1 emits frag-order hi/lo directly)
//  - conv1/conv4/conv5/fc3 unchanged from R3 (known good)
// ---------------------------------------------------------------------------

#define EPS 1e-5f

typedef __attribute__((ext_vector_type(8))) short bf16x8;
typedef __attribute__((ext_vector_type(4))) float f32x4;
typedef __attribute__((ext_vector_type(16))) float f32x16;
typedef __attribute__((ext_vector_type(4))) int i32x4;

__device__ __forceinline__ short f2bf(float f) {
  unsigned u = __builtin_bit_cast(unsigned, f);
  unsigned r = u + 0x7FFFu + ((u >> 16) & 1u);   // RNE
  return (short)(r >> 16);
}
__device__ __forceinline__ float bf2f(short h) {
  unsigned u = ((unsigned)(unsigned short)h) << 16;
  return __builtin_bit_cast(float, u);
}
__device__ __forceinline__ int swz(int pin, int smask) {
  return (pin ^ (pin >> 2)) & smask;   // uniform bank-quad spread (enumerated)
}

// ---------------- weight fake-quant: per-output-channel scale + dequant -----
struct QuantArgs {
  const float* w[8];
  float* q[8];     // dequantized fp32 (nullptr if not needed)
  float* sc[8];    // per-channel scale out
  int cik[8];
  int cum[9];
};

__global__ __launch_bounds__(256) void quant_all(QuantArgs a) {
  int b = blockIdx.x;
  int t = 0;
  while (b >= a.cum[t + 1]) t++;
  int co = b - a.cum[t];
  int cik = a.cik[t];
  const float* src = a.w[t] + (size_t)co * cik;
  float m = 0.f;
  for (int i = threadIdx.x; i < cik; i += 256) m = fmaxf(m, fabsf(src[i]));
  #pragma unroll
  for (int o = 1; o < 64; o <<= 1) m = fmaxf(m, __shfl_xor(m, o));
  __shared__ float red[4];
  __shared__ float ssh;
  if ((threadIdx.x & 63) == 0) red[threadIdx.x >> 6] = m;
  __syncthreads();
  if (threadIdx.x == 0) {
    m = fmaxf(fmaxf(red[0], red[1]), fmaxf(red[2], red[3]));
    float s = fmaxf(m / 127.0f, 1e-8f);
    ssh = s;
    a.sc[t][co] = s;
  }
  __syncthreads();
  float s = ssh;
  float* dst = a.q[t];
  if (dst) {
    float* d = dst + (size_t)co * cik;
    for (int i = threadIdx.x; i < cik; i += 256) {
      float q = rintf(src[i] / s);
      q = fminf(fmaxf(q, -128.f), 127.f);
      d[i] = q * s;
    }
  }
}

// ---------------- conv1 weights -> int-bf16 frag order (16x16) --------------
__global__ __launch_bounds__(256) void repack_c1(const float* __restrict__ w,
                                                 const float* __restrict__ sc,
                                                 short* __restrict__ dst) {
  int i = blockIdx.x * 256 + threadIdx.x;      // 32 oc x 32 taps
  if (i >= 1024) return;
  int oc = i >> 5, t = i & 31;
  float v = 0.f;
  if (t < 25) {
    float s = sc[oc];
    v = fminf(fmaxf(rintf(w[oc * 25 + t] / s), -128.f), 127.f);
  }
  dst[(((oc >> 4) * 4 + (t >> 3)) * 16 + (oc & 15)) * 8 + (t & 7)] = f2bf(v);
}

// ---- conv4 weights -> int-bf16 16x16 frag order [chunk][kk][nt][ks][q][mr][j]
__global__ __launch_bounds__(256) void repack_frag(const float* __restrict__ w,
                                                   const float* __restrict__ sc,
                                                   short* __restrict__ dst,
                                                   int CO, int CI, int KK, int OCCH) {
  int i = blockIdx.x * 256 + threadIdx.x;
  int total = CO * CI * KK;
  if (i >= total) return;
  int oc = i / (CI * KK);
  int r = i - oc * (CI * KK);
  int ci = r / KK;
  int kk = r - ci * KK;
  float s = sc[oc];
  float q = fminf(fmaxf(rintf(w[i] / s), -128.f), 127.f);
  int NTC = OCCH >> 4;
  int KS = CI >> 5; if (KS == 0) KS = 1;
  int chunk = oc / OCCH;
  int ocl = oc - chunk * OCCH;
  int ntl = ocl >> 4, mr = ocl & 15;
  int ks = ci >> 5, qq = (ci >> 3) & 3, j = ci & 7;
  size_t d = ((((((size_t)(chunk * KK + kk) * NTC + ntl) * KS + ks) * 4 + qq) * 16 + mr)) * 8 + j;
  dst[d] = f2bf(q);
}

// ---- conv2/3 weights -> int-bf16 32x32 frag order [ch][kk][nt][ks16][lane][j]
__global__ __launch_bounds__(256) void repack_frag32(const float* __restrict__ w,
                                                     const float* __restrict__ sc,
                                                     short* __restrict__ dst,
                                                     int CO, int CI, int KK, int OCCH) {
  int i = blockIdx.x * 256 + threadIdx.x;
  int total = CO * CI * KK;
  if (i >= total) return;
  int oc = i / (CI * KK);
  int r = i - oc * (CI * KK);
  int ci = r / KK;
  int kk = r - ci * KK;
  float s = sc[oc];
  float q = fminf(fmaxf(rintf(w[i] / s), -128.f), 127.f);
  int NT32 = OCCH >> 5;
  int KS16 = CI >> 4;
  int chunk = oc / OCCH;
  int ocl = oc - chunk * OCCH;
  int nt = ocl >> 5, n32 = ocl & 31;
  int ks = ci >> 4, hh = (ci >> 3) & 1, j = ci & 7;
  size_t d = ((((size_t)(chunk * KK + kk) * NT32 + nt) * KS16 + ks) * 64 + hh * 32 + n32) * 8 + j;
  dst[d] = f2bf(q);
}

// ---- fc weights -> int-bf16 block-frag order [nblk][kc][nt][ks][q][mr][j] ---
__global__ __launch_bounds__(256) void repack_fc(const float* __restrict__ w,
                                                 const float* __restrict__ sc,
                                                 short* __restrict__ dst,
                                                 int K, int KC, int total) {
  int i = blockIdx.x * 256 + threadIdx.x;
  if (i >= total) return;
  int n = i / K, k = i - n * K;
  float s = sc[n];
  float q = fminf(fmaxf(rintf(w[i] / s), -128.f), 127.f);
  int nblk = n >> 6, ntl = (n >> 4) & 3, mr = n & 15;
  int kc = k >> 7, ks = (k >> 5) & 3, qq = (k >> 3) & 3, j = k & 7;
  size_t d = (((((((size_t)nblk * KC + kc) * 4 + ntl) * 4 + ks) * 4 + qq) * 16 + mr)) * 8 + j;
  dst[d] = f2bf(q);
}

// ---------------- transpose w5: [oc][ci] -> [ci][oc] (fp32) ----------------
__global__ __launch_bounds__(256) void transpose_w5(const float* __restrict__ src,
                                                    float* __restrict__ dst) {
  int i = blockIdx.x * 256 + threadIdx.x;    // 65536
  int oc = i >> 8, ci = i & 255;
  dst[ci * 256 + oc] = src[i];
}

// ------ fold BN (+conv bias, + int-weight scale) into per-channel A,B ------
struct BnArgs {
  const float* p[7][5];   // b, g, be, mu, va
  const float* wsc;
  float* ab;
  int C[7];
  int abo[7];
  int sco[7];
  int us[7];
  int cum[8];
};

__global__ __launch_bounds__(256) void bn_all(BnArgs a) {
  int i = blockIdx.x * 256 + threadIdx.x;
  if (i >= a.cum[7]) return;
  int t = 0;
  while (i >= a.cum[t + 1]) t++;
  int c = i - a.cum[t];
  float A = a.p[t][1][c] / sqrtf(a.p[t][4][c] + EPS);
  float B = (a.p[t][0][c] - a.p[t][3][c]) * A + a.p[t][2][c];
  float As = a.us[t] ? A * a.wsc[a.sco[t] + c] : A;
  a.ab[a.abo[t] + c] = As;
  a.ab[a.abo[t] + a.C[t] + c] = B;
}

// ---------------- conv1: MFMA via im2col in LDS (16x16x32) -----------------
__global__ __launch_bounds__(448, 2) void conv1_mfma(
    const float* __restrict__ x, const short* __restrict__ wb1,
    const float* __restrict__ ab, short* __restrict__ out) {
  __shared__ __align__(16) float sx[784];
  __shared__ __align__(16) short sim[784 * 32];
  __shared__ __align__(16) short sw1[1024];
  const int tid = threadIdx.x;
  const int img = blockIdx.x;
  for (int i = tid; i < 784; i += 448) sx[i] = x[(size_t)img * 784 + i];
  for (int i = tid; i < 1024; i += 448) sw1[i] = wb1[i];
  __syncthreads();
  for (int i = tid; i < 25088; i += 448) {
    int p = i >> 5, t = i & 31;
    short v = 0;
    if (t < 25) {
      int py = p / 28, px = p - py * 28;
      int iy = py + t / 5 - 2, ix = px + t % 5 - 2;
      if ((unsigned)iy < 28u && (unsigned)ix < 28u) v = f2bf(sx[iy * 28 + ix]);
    }
    sim[i] = v;
  }
  __syncthreads();
  const int lane = tid & 63, wv = tid >> 6;
  const int mrow = lane & 15, quad = lane >> 4;
  f32x4 acc[7][2];
  #pragma unroll
  for (int i = 0; i < 7; ++i) {
    acc[i][0] = (f32x4){0.f, 0.f, 0.f, 0.f};
    acc[i][1] = (f32x4){0.f, 0.f, 0.f, 0.f};
  }
  #pragma unroll
  for (int i = 0; i < 7; ++i) {
    const int mt = wv * 7 + i;
    const bf16x8 a = *(const bf16x8*)&sim[(mt * 16 + mrow) * 32 + quad * 8];
    #pragma unroll
    for (int nt = 0; nt < 2; ++nt) {
      const bf16x8 b = *(const bf16x8*)&sw1[(nt * 4 + quad) * 128 + mrow * 8];
      acc[i][nt] = __builtin_amdgcn_mfma_f32_16x16x32_bf16(a, b, acc[i][nt], 0, 0, 0);
    }
  }
  #pragma unroll
  for (int i = 0; i < 7; ++i) {
    const int mt = wv * 7 + i;
    #pragma unroll
    for (int nt = 0; nt < 2; ++nt) {
      const int oc = nt * 16 + mrow;
      const float A = ab[oc], Bc = ab[32 + oc];
      #pragma unroll
      for (int r = 0; r < 4; ++r) {
        const int p = mt * 16 + quad * 4 + r;
        float v = fminf(fmaxf(acc[i][nt][r] * A + Bc, -1.f), 1.f);
        out[((size_t)img * 784 + p) * 32 + oc] = f2bf(v);
      }
    }
  }
}

// -------- conv2/conv3: 32x32x16 MFMA, tap-group weights, pool in-register ---
// in: bf16 NHWC; wfrag: 32-frag order; out: bf16 NHWC pooled
template <int CIN, int COUT, int KW, int PAD, int IN_W, int PW, int IMGS,
          int TPI, int MTW, int OCCH, int TG>
__global__ __launch_bounds__(448, 2) void conv23_mfma32(
    const short* __restrict__ in, const short* __restrict__ wfrag,
    const float* __restrict__ ab, short* __restrict__ out) {
  constexpr int S = CIN / 8;
  constexpr int KS16 = CIN / 16;
  constexpr int NT32 = OCCH / 32;
  constexpr int NPIX = IN_W * IN_W;
  constexpr int PP = PW * PW;
  constexpr int KK = KW * KW;
  constexpr int CHUNKS = COUT / OCCH;
  constexpr int NGRP = KK / TG;
  constexpr int WG = TG * NT32 * KS16 * 512;      // shorts per tap-group
  constexpr int ITEMS = IMGS * TPI;
  constexpr int INCH = IMGS * NPIX * S;           // 16B input units

  __shared__ __align__(16) short simg[IMGS * NPIX * CIN];
  __shared__ __align__(16) short sw[WG];
  __shared__ __align__(16) short zfrag[8];

  const int tid = threadIdx.x;
  const int img0 = blockIdx.x * IMGS;
  const int lane = tid & 63, wv = tid >> 6;
  const int l31 = lane & 31, h = lane >> 5;

  if (tid < 8) zfrag[tid] = 0;

  // per-tile geometry
  int yy[MTW], xx[MTW], ibs[MTW], lt_[MTW], il_[MTW];
  bool rv[MTW], uv[MTW];
  #pragma unroll
  for (int i = 0; i < MTW; ++i) {
    int u = wv + i * 7;
    uv[i] = u < ITEMS;
    int uu = uv[i] ? u : 0;
    int il = uu / TPI, lt = uu - il * TPI;
    int m = lt * 32 + l31;
    int pp = m >> 2, cd = m & 3;
    rv[i] = uv[i] && (pp < PP);
    int py = pp / PW, px = pp - py * PW;
    yy[i] = py * 2 + (cd >> 1);
    xx[i] = px * 2 + (cd & 1);
    ibs[i] = il * (NPIX * S);
    lt_[i] = lt; il_[i] = il;
  }

  // stage input once (16B units, quad-hash swizzle)
  {
    const i32x4* gsrc = (const i32x4*)(in + (size_t)img0 * NPIX * CIN);
    for (int c = tid; c < INCH; c += 448) {
      int il = c / (NPIX * S);
      int r = c - il * (NPIX * S);
      int pix = r / S;
      int blk = r & (S - 1);
      ((i32x4*)simg)[il * (NPIX * S) + pix * S + (blk ^ swz(pix, S - 1))] = gsrc[c];
    }
  }

  for (int ch = 0; ch < CHUNKS; ++ch) {
    f32x16 acc[MTW][NT32];
    #pragma unroll
    for (int i = 0; i < MTW; ++i)
      #pragma unroll
      for (int nt = 0; nt < NT32; ++nt)
        #pragma unroll
        for (int e = 0; e < 16; ++e) acc[i][nt][e] = 0.f;

    for (int tg = 0; tg < NGRP; ++tg) {
      __syncthreads();
      const i32x4* wsrc = (const i32x4*)(wfrag +
          ((size_t)ch * KK + tg * TG) * (NT32 * KS16 * 512));
      for (int u2 = tid; u2 < WG / 8; u2 += 448) ((i32x4*)sw)[u2] = wsrc[u2];
      __syncthreads();

      #pragma unroll
      for (int tt = 0; tt < TG; ++tt) {
        const int t = tg * TG + tt;
        const int dy = t / KW - PAD, dx = t % KW - PAD;
        int aoff[MTW], sx[MTW];
        #pragma unroll
        for (int i = 0; i < MTW; ++i) {
          int iy = yy[i] + dy, ix = xx[i] + dx;
          bool ok = rv[i] && ((unsigned)iy < (unsigned)IN_W) &&
                    ((unsigned)ix < (unsigned)IN_W);
          int pin = iy * IN_W + ix;
          aoff[i] = ok ? (ibs[i] + pin * S) * 8 : -1;
          sx[i] = swz(pin, S - 1);
        }
        #pragma unroll
        for (int ks = 0; ks < KS16; ++ks) {
          bf16x8 af[MTW];
          #pragma unroll
          for (int i = 0; i < MTW; ++i) {
            const short* p = (aoff[i] >= 0)
                ? &simg[aoff[i] + (((ks * 2 + h) ^ sx[i]) * 8)] : zfrag;
            af[i] = *(const bf16x8*)p;
          }
          #pragma unroll
          for (int nt = 0; nt < NT32; ++nt) {
            const bf16x8 bf = *(const bf16x8*)&sw[
                (((tt * NT32 + nt) * KS16 + ks) * 64 + lane) * 8];
            #pragma unroll
            for (int i = 0; i < MTW; ++i)
              acc[i][nt] = __builtin_amdgcn_mfma_f32_32x32x16_bf16(
                  af[i], bf, acc[i][nt], 0, 0, 0);
          }
        }
      }
    }

    // epilogue: lane holds 4 pooled pixels (g) x 4 candidates (reg&3)
    #pragma unroll
    for (int i = 0; i < MTW; ++i) {
      #pragma unroll
      for (int nt = 0; nt < NT32; ++nt) {
        const int oc = ch * OCCH + nt * 32 + l31;
        const float A = ab[oc], Bc = ab[COUT + oc];
        #pragma unroll
        for (int g = 0; g < 4; ++g) {
          const int ppo = lt_[i] * 8 + 2 * g + h;
          if (uv[i] && ppo < PP) {
            float mx = fmaxf(fmaxf(acc[i][nt][g * 4 + 0], acc[i][nt][g * 4 + 1]),
                             fmaxf(acc[i][nt][g * 4 + 2], acc[i][nt][g * 4 + 3]));
            float v = fminf(fmaxf(mx * A + Bc, -1.f), 1.f);
            out[((size_t)(img0 + il_[i]) * PP + ppo) * COUT + oc] = f2bf(v);
          }
        }
      }
    }
  }
}

// -------- conv4: tap-outer, double-buffered tap weights, fp32 NHWC out ------
__global__ __launch_bounds__(512, 2) void conv4_mfma(
    const short* __restrict__ in,      // h3 bf16 [img][49][128]
    const short* __restrict__ wfrag,   // [9][16][4][4][16][8]
    const float* __restrict__ ab, float* __restrict__ out) {
  constexpr int S = 16, NPIX = 49, PP = 9;
  __shared__ __align__(16) short simg[2 * NPIX * 128];
  __shared__ __align__(16) short swb[2][32768];
  const int tid = threadIdx.x;
  const int img0 = blockIdx.x * 2;
  const int lane = tid & 63, wv = tid >> 6;
  const int mrow = lane & 15, quad = lane >> 4;

  {
    const i32x4* gsrc = (const i32x4*)(in + (size_t)img0 * NPIX * 128);
    for (int c = tid; c < 2 * NPIX * S; c += 512) {
      int il = c / (NPIX * S);
      int r = c - il * (NPIX * S);
      int pix = r >> 4, blk = r & 15;
      ((i32x4*)simg)[il * NPIX * S + pix * S + (blk ^ (pix & 15))] = gsrc[c];
    }
    for (int u = tid; u < 4096; u += 512)
      ((i32x4*)swb[0])[u] = ((const i32x4*)wfrag)[u];
  }

  int yy[6], xx[6], ibs[6], ppo_[6], ilv[6];
  bool rv[6], pv[6];
  #pragma unroll
  for (int i = 0; i < 6; ++i) {
    int il = i / 3, lt = i - il * 3;
    int m = lt * 16 + mrow;
    int pp = m >> 2, cd = m & 3;
    rv[i] = pp < PP;
    int py = pp / 3, px = pp - py * 3;
    yy[i] = py * 2 + (cd >> 1);
    xx[i] = px * 2 + (cd & 1);
    ibs[i] = il * NPIX * S;
    ilv[i] = il;
    ppo_[i] = lt * 4 + quad;
    pv[i] = ppo_[i] < PP;
  }
  const int nt0 = wv, nt1 = wv + 8;
  f32x4 acc[6][2];
  #pragma unroll
  for (int i = 0; i < 6; ++i) {
    acc[i][0] = (f32x4){0.f, 0.f, 0.f, 0.f};
    acc[i][1] = (f32x4){0.f, 0.f, 0.f, 0.f};
  }
  __syncthreads();

  int dy = -1, dx = -1;
  for (int t = 0; t < 9; ++t) {
    const int buf = t & 1;
    if (t < 8) {
      const i32x4* wsrc = (const i32x4*)(wfrag + (size_t)(t + 1) * 32768);
      for (int u = tid; u < 4096; u += 512) ((i32x4*)swb[buf ^ 1])[u] = wsrc[u];
    }
    #pragma unroll
    for (int ks = 0; ks < 4; ++ks) {
      bf16x8 af[6];
      #pragma unroll
      for (int i = 0; i < 6; ++i) {
        int iy = yy[i] + dy, ix = xx[i] + dx;
        bool ok = rv[i] && (unsigned)iy < 7u && (unsigned)ix < 7u;
        int pin = iy * 7 + ix;
        int blk = (ks * 4 + quad) ^ (pin & 15);
        af[i] = ok ? *(const bf16x8*)&simg[(ibs[i] + pin * S + blk) * 8]
                   : (bf16x8){0, 0, 0, 0, 0, 0, 0, 0};
      }
      const bf16x8 b0 = *(const bf16x8*)&swb[buf][((nt0 * 4 + ks) * 4 + quad) * 128 + mrow * 8];
      const bf16x8 b1 = *(const bf16x8*)&swb[buf][((nt1 * 4 + ks) * 4 + quad) * 128 + mrow * 8];
      #pragma unroll
      for (int i = 0; i < 6; ++i) {
        acc[i][0] = __builtin_amdgcn_mfma_f32_16x16x32_bf16(af[i], b0, acc[i][0], 0, 0, 0);
        acc[i][1] = __builtin_amdgcn_mfma_f32_16x16x32_bf16(af[i], b1, acc[i][1], 0, 0, 0);
      }
    }
    dx++;
    if (dx == 2) { dx = -1; dy++; }
    __syncthreads();
  }

  #pragma unroll
  for (int i = 0; i < 6; ++i) {
    if (pv[i]) {
      #pragma unroll
      for (int nj = 0; nj < 2; ++nj) {
        const int oc = (nj ? nt1 : nt0) * 16 + mrow;
        const f32x4 a = acc[i][nj];
        float mx = fmaxf(fmaxf(a[0], a[1]), fmaxf(a[2], a[3]));
        float v = fminf(fmaxf(mx * ab[oc] + ab[256 + oc], -1.f), 1.f);
        out[((size_t)(img0 + ilv[i]) * PP + ppo_[i]) * 256 + oc] = v;
      }
    }
  }
}

// ------ conv5 (1x1) fp32 VALU; writes h5 hi/lo bf16 in fc1 frag order -------
__global__ __launch_bounds__(256, 2) void conv5_fc(
    const float* __restrict__ in, const float* __restrict__ w5t,
    const float* __restrict__ ab, short* __restrict__ oh, short* __restrict__ ol) {
  __shared__ float sin[9 * 256];
  const int img = blockIdx.x;
  const int oc = threadIdx.x;
  for (int i = threadIdx.x; i < 2304; i += 256)
    sin[i] = in[(size_t)img * 2304 + i];
  __syncthreads();
  float acc[9];
  #pragma unroll
  for (int p = 0; p < 9; ++p) acc[p] = 0.f;
  for (int ci = 0; ci < 256; ++ci) {
    const float wv = w5t[ci * 256 + oc];
    #pragma unroll
    for (int p = 0; p < 9; ++p) acc[p] += sin[p * 256 + ci] * wv;
  }
  const float A = ab[oc], Bc = ab[256 + oc];
  const int mblk = img >> 6, mtq = (img >> 4) & 3, mr = img & 15;
  #pragma unroll
  for (int p = 0; p < 9; ++p) {
    float v = fminf(fmaxf(acc[p] * A + Bc, -1.f), 1.f);
    int k = oc * 9 + p;
    int kc = k >> 7, ks = (k >> 5) & 3, qq = (k >> 3) & 3, j = k & 7;
    size_t d = (((((((size_t)mblk * 18 + kc) * 4 + mtq) * 4 + ks) * 4 + qq) * 16 + mr)) * 8 + j;
    short hi = f2bf(v);
    oh[d] = hi;
    ol[d] = f2bf(v - bf2f(hi));
  }
}

// ------- fc MFMA GEMM: X hi/lo frag order, int-bf16 W frag order, bn+ht -----
// OUTMODE 0: write hi/lo frag order for next fc (KC2); 1: fp32 row-major.
template <int KC, int OUTMODE, int KC2, int NALL>
__global__ __launch_bounds__(256, 2) void fc_mfma(
    const short* __restrict__ Xh, const short* __restrict__ Xl,
    const short* __restrict__ Wf, const float* __restrict__ ab,
    float* __restrict__ outF, short* __restrict__ outH, short* __restrict__ outL) {
  __shared__ __align__(16) short sxh[8192];
  __shared__ __align__(16) short sxl[8192];
  __shared__ __align__(16) short swt[8192];
  const int tid = threadIdx.x;
  const int bn = blockIdx.x, bm = blockIdx.y;
  const int lane = tid & 63, wv = tid >> 6;
  const int mrow = lane & 15, quad = lane >> 4;
  f32x4 acc[4];
  #pragma unroll
  for (int nt = 0; nt < 4; ++nt) acc[nt] = (f32x4){0.f, 0.f, 0.f, 0.f};
  for (int kc = 0; kc < KC; ++kc) {
    __syncthreads();
    {
      const size_t xo = ((size_t)bm * KC + kc) * 8192;
      const size_t wo = ((size_t)bn * KC + kc) * 8192;
      #pragma unroll
      for (int u = 0; u < 4; ++u) {
        ((i32x4*)sxh)[tid + u * 256] = ((const i32x4*)(Xh + xo))[tid + u * 256];
        ((i32x4*)sxl)[tid + u * 256] = ((const i32x4*)(Xl + xo))[tid + u * 256];
        ((i32x4*)swt)[tid + u * 256] = ((const i32x4*)(Wf + wo))[tid + u * 256];
      }
    }
    __syncthreads();
    #pragma unroll
    for (int ks = 0; ks < 4; ++ks) {
      const int ao = (((wv * 4 + ks) * 4 + quad) * 16 + mrow) * 8;
      const bf16x8 ah = *(const bf16x8*)&sxh[ao];
      const bf16x8 al = *(const bf16x8*)&sxl[ao];
      #pragma unroll
      for (int nt = 0; nt < 4; ++nt) {
        const bf16x8 b = *(const bf16x8*)&swt[(((nt * 4 + ks) * 4 + quad) * 16 + mrow) * 8];
        acc[nt] = __builtin_amdgcn_mfma_f32_16x16x32_bf16(ah, b, acc[nt], 0, 0, 0);
        acc[nt] = __builtin_amdgcn_mfma_f32_16x16x32_bf16(al, b, acc[nt], 0, 0, 0);
      }
    }
  }
  #pragma unroll
  for (int nt = 0; nt < 4; ++nt) {
    const int n = bn * 64 + nt * 16 + mrow;
    const float A = ab[n], Bc = ab[NALL + n];
    #pragma unroll
    for (int r = 0; r < 4; ++r) {
      const int m = bm * 64 + wv * 16 + quad * 4 + r;
      float v = fminf(fmaxf(acc[nt][r] * A + Bc, -1.f), 1.f);
      if (OUTMODE == 0) {
        size_t d = (((((((size_t)(m >> 6) * KC2 + (n >> 7)) * 4 + ((m >> 4) & 3)) * 4 +
                       ((n >> 5) & 3)) * 4 + ((n >> 3) & 3)) * 16 + (m & 15))) * 8 + (n & 7);
        short hi = f2bf(v);
        outH[d] = hi;
        outL[d] = f2bf(v - bf2f(hi));
      } else {
        outF[(size_t)m * NALL + n] = v;
      }
    }
  }
}

// ---------------- FC3 ----------------
__global__ __launch_bounds__(256) void fc3_kernel(
    const float* __restrict__ X, const float* __restrict__ W,
    const float* __restrict__ bias, float* __restrict__ out) {
  __shared__ float ws[512 * 10 + 16];
  for (int li = threadIdx.x; li < 5120; li += 256) {
    int n = li / 512, k = li - n * 512;
    ws[k * 10 + n] = W[li];
  }
  __syncthreads();
  const int il = threadIdx.x >> 4, n = threadIdx.x & 15;
  const int img = blockIdx.x * 16 + il;
  if (n < 10) {
    const float* xp = X + (size_t)img * 512;
    float s = 0.f;
    for (int k = 0; k < 512; ++k) s += xp[k] * ws[k * 10 + n];
    out[img * 10 + n] = s + bias[n];
  }
}

// ---------------- launch ----------------
extern "C" void kernel_launch(void* const* d_in, const int* in_sizes, int n_in,
                              void* d_out, int out_size, void* d_ws, size_t ws_size,
                              hipStream_t stream) {
  (void)in_sizes; (void)n_in; (void)out_size; (void)ws_size;
  const float* x = (const float*)d_in[0];
  float* W = (float*)d_ws;

  // workspace layout (floats, 16B-aligned offsets)
  float* wsc  = W + 0;                       // 2304
  float* ab   = W + 2304;                    // 4608
  float* qs5  = W + 6912;                    // 65536
  float* fq3  = W + 72448;                   // 5120
  short* wb1  = (short*)(W + 77568);         // 1024 sh
  short* wb2  = (short*)(W + 78080);         // 51200 sh
  short* wb3  = (short*)(W + 103680);        // 73728 sh
  short* wb4  = (short*)(W + 140544);        // 294912 sh
  float* w5t  = W + 288000;                  // 65536
  short* fqb1 = (short*)(W + 353536);        // 2359296 sh
  short* fqb2 = (short*)(W + 1533184);       // 524288 sh
  short* h1   = (short*)(W + 1795328);       // [1024][784][32] bf16
  short* h2   = (short*)(W + 14640384);      // [1024][196][64] bf16
  short* h3   = (short*)(W + 21062912);      // [1024][49][128] bf16
  float* h4   = W + 24274176;                // [1024][9][256] fp32
  short* h5h  = (short*)(W + 26633472);      // frag order bf16 hi
  short* h5l  = (short*)(W + 27813120);      // frag order bf16 lo
  short* f1h  = (short*)(W + 28992768);      // frag order bf16 hi
  short* f1l  = (short*)(W + 29517056);      // frag order bf16 lo
  float* f2   = W + 30041344;                // [1024][512]

  // 1) fake-quant: scales for all; dequant only for conv5 (qs5) and fc3 (fq3)
  QuantArgs qa;
  const int widx[8] = {1, 7, 13, 19, 25, 31, 37, 43};
  float* qdst[8] = {nullptr, nullptr, nullptr, nullptr, qs5, nullptr, nullptr, fq3};
  const int sco8[8] = {0, 32, 96, 224, 480, 736, 1760, 2272};
  const int cik[8] = {25, 800, 576, 1152, 256, 2304, 1024, 512};
  const int co[8] = {32, 64, 128, 256, 256, 1024, 512, 10};
  int cum = 0;
  for (int i = 0; i < 8; ++i) {
    qa.w[i] = (const float*)d_in[widx[i]];
    qa.q[i] = qdst[i];
    qa.sc[i] = wsc + sco8[i];
    qa.cik[i] = cik[i];
    qa.cum[i] = cum;
    cum += co[i];
  }
  qa.cum[8] = cum;
  hipLaunchKernelGGL(quant_all, dim3(cum), dim3(256), 0, stream, qa);

  // 2) repack int-bf16 frag-order weights
  hipLaunchKernelGGL(repack_c1, dim3(4), dim3(256), 0, stream,
                     (const float*)d_in[1], wsc + 0, wb1);
  hipLaunchKernelGGL(repack_frag32, dim3(200), dim3(256), 0, stream,
                     (const float*)d_in[7], wsc + 32, wb2, 64, 32, 25, 64);
  hipLaunchKernelGGL(repack_frag32, dim3(288), dim3(256), 0, stream,
                     (const float*)d_in[13], wsc + 96, wb3, 128, 64, 9, 64);
  hipLaunchKernelGGL(repack_frag, dim3(1152), dim3(256), 0, stream,
                     (const float*)d_in[19], wsc + 224, wb4, 256, 128, 9, 256);
  hipLaunchKernelGGL(repack_fc, dim3(9216), dim3(256), 0, stream,
                     (const float*)d_in[31], wsc + 736, fqb1, 2304, 18, 1024 * 2304);
  hipLaunchKernelGGL(repack_fc, dim3(2048), dim3(256), 0, stream,
                     (const float*)d_in[37], wsc + 1760, fqb2, 1024, 8, 512 * 1024);
  hipLaunchKernelGGL(transpose_w5, dim3(256), dim3(256), 0, stream, qs5, w5t);

  // 3) fold BN (+ int-weight scale for conv1-4, fc1, fc2)
  BnArgs ba;
  const int bbase[7] = {2, 8, 14, 20, 26, 32, 38};
  const int bc[7] = {32, 64, 128, 256, 256, 1024, 512};
  const int abo[7] = {0, 64, 192, 448, 960, 1472, 3520};
  const int us7[7] = {1, 1, 1, 1, 0, 1, 1};
  int bcum = 0;
  for (int t = 0; t < 7; ++t) {
    for (int j = 0; j < 5; ++j) ba.p[t][j] = (const float*)d_in[bbase[t] + j];
    ba.C[t] = bc[t];
    ba.abo[t] = abo[t];
    ba.sco[t] = sco8[t];
    ba.us[t] = us7[t];
    ba.cum[t] = bcum;
    bcum += bc[t];
  }
  ba.cum[7] = bcum;
  ba.ab = ab;
  ba.wsc = wsc;
  hipLaunchKernelGGL(bn_all, dim3((bcum + 255) / 256), dim3(256), 0, stream, ba);

  // 4) conv stack
  hipLaunchKernelGGL(conv1_mfma, dim3(1024), dim3(448), 0, stream,
                     x, wb1, ab + 0, h1);
  hipLaunchKernelGGL((conv23_mfma32<32, 64, 5, 2, 28, 14, 1, 25, 4, 64, 5>),
                     dim3(1024), dim3(448), 0, stream, h1, wb2, ab + 64, h2);
  hipLaunchKernelGGL((conv23_mfma32<64, 128, 3, 1, 14, 7, 2, 7, 2, 64, 3>),
                     dim3(512), dim3(448), 0, stream, h2, wb3, ab + 192, h3);
  hipLaunchKernelGGL(conv4_mfma, dim3(512), dim3(512), 0, stream,
                     h3, wb4, ab + 448, h4);
  hipLaunchKernelGGL(conv5_fc, dim3(1024), dim3(256), 0, stream,
                     h4, w5t, ab + 960, h5h, h5l);

  // 5) FC stack
  hipLaunchKernelGGL((fc_mfma<18, 0, 8, 1024>), dim3(16, 16), dim3(256), 0, stream,
                     h5h, h5l, fqb1, ab + 1472, nullptr, f1h, f1l);
  hipLaunchKernelGGL((fc_mfma<8, 1, 0, 512>), dim3(8, 16), dim3(256), 0, stream,
                     f1h, f1l, fqb2, ab + 3520, f2, nullptr, nullptr);
  hipLaunchKernelGGL(fc3_kernel, dim3(64), dim3(256), 0, stream,
                     f2, fq3, (const float*)d_in[44], (float*)d_out);
}

// Round 6
// 436.615 us; speedup vs baseline: 11.3939x; 1.0886x over previous
//
#include <hip/hip_runtime.h>
#include <hip/hip_bf16.h>
#include <math.h>

// ---------------------------------------------------------------------------
// BinaryCNN round 6 (= R5 with workspace-overlap fix):
//  - conv2: half-image 256-thr blocks (128 AGPR acc + ~100 VGPR = 2 blk/CU)
//  - conv3: 256-thr blocks, 2 imgs, MTW=4 (2 blk/CU)
//  - conv5 -> MFMA fc-GEMM (conv4 emits hi/lo frag h4); exact-int w5
//  - all weight prep fused into one kernel (prep_all)
//  - FIX: f1h/f1l/f2 offsets (R5 aliased f1l over f1h: 524288-float stride,
//    not 262144 — shorts-vs-floats slip)
// ---------------------------------------------------------------------------

#define EPS 1e-5f

typedef __attribute__((ext_vector_type(8))) short bf16x8;
typedef __attribute__((ext_vector_type(4))) float f32x4;
typedef __attribute__((ext_vector_type(16))) float f32x16;
typedef __attribute__((ext_vector_type(4))) int i32x4;

__device__ __forceinline__ short f2bf(float f) {
  unsigned u = __builtin_bit_cast(unsigned, f);
  unsigned r = u + 0x7FFFu + ((u >> 16) & 1u);   // RNE
  return (short)(r >> 16);
}
__device__ __forceinline__ float bf2f(short h) {
  unsigned u = ((unsigned)(unsigned short)h) << 16;
  return __builtin_bit_cast(float, u);
}
__device__ __forceinline__ int swz(int pin, int smask) {
  return (pin ^ (pin >> 2)) & smask;   // uniform bank-quad spread
}
__device__ __forceinline__ float qclip(float w, float s) {
  return fminf(fmaxf(rintf(w / s), -128.f), 127.f);
}

// ---------------- fused prep: scales + all weight repacks -------------------
// kind: 0=conv1 c1-frag, 1=frag32 (conv2/3), 2=frag16 (conv4), 3=fc-frag,
//       4=dequant fp32 (fc3)
struct PrepArgs {
  const float* w[8];
  short* dsth[8];
  float* dstf;
  float* sc;
  int sco[8];
  int cik[8];
  int kind[8];
  int KK[8];
  int CI[8];
  int OCCH[8];
  int KC[8];
  int cum[9];
};

__global__ __launch_bounds__(256) void prep_all(PrepArgs a) {
  int b = blockIdx.x;
  int t = 0;
  while (b >= a.cum[t + 1]) t++;
  int oc = b - a.cum[t];
  int cik = a.cik[t];
  const float* src = a.w[t] + (size_t)oc * cik;
  float m = 0.f;
  for (int i = threadIdx.x; i < cik; i += 256) m = fmaxf(m, fabsf(src[i]));
  #pragma unroll
  for (int o = 1; o < 64; o <<= 1) m = fmaxf(m, __shfl_xor(m, o));
  __shared__ float red[4];
  __shared__ float ssh;
  if ((threadIdx.x & 63) == 0) red[threadIdx.x >> 6] = m;
  __syncthreads();
  if (threadIdx.x == 0) {
    m = fmaxf(fmaxf(red[0], red[1]), fmaxf(red[2], red[3]));
    float s = fmaxf(m / 127.0f, 1e-8f);
    ssh = s;
    a.sc[a.sco[t] + oc] = s;
  }
  __syncthreads();
  const float s = ssh;
  const int kind = a.kind[t];
  short* dst = a.dsth[t];
  if (kind == 0) {
    for (int tt = threadIdx.x; tt < 32; tt += 256) {
      float q = (tt < 25) ? qclip(src[tt], s) : 0.f;
      dst[(((oc >> 4) * 4 + (tt >> 3)) * 16 + (oc & 15)) * 8 + (tt & 7)] = f2bf(q);
    }
  } else if (kind == 1) {
    const int KK = a.KK[t], CI = a.CI[t], OCCH = a.OCCH[t];
    const int NT32 = OCCH >> 5, KS16 = CI >> 4;
    const int chunk = oc / OCCH, ocl = oc - chunk * OCCH;
    const int nt = ocl >> 5, n32 = ocl & 31;
    for (int idx = threadIdx.x; idx < cik; idx += 256) {
      int ci = idx / KK, kk = idx - ci * KK;
      float q = qclip(src[idx], s);
      int ks = ci >> 4, hh = (ci >> 3) & 1, j = ci & 7;
      size_t d = ((((size_t)(chunk * KK + kk) * NT32 + nt) * KS16 + ks) * 64 +
                  hh * 32 + n32) * 8 + j;
      dst[d] = f2bf(q);
    }
  } else if (kind == 2) {
    const int KK = a.KK[t], CI = a.CI[t], OCCH = a.OCCH[t];
    const int NTC = OCCH >> 4, KS = CI >> 5;
    const int chunk = oc / OCCH, ocl = oc - chunk * OCCH;
    const int ntl = ocl >> 4, mr = ocl & 15;
    for (int idx = threadIdx.x; idx < cik; idx += 256) {
      int ci = idx / KK, kk = idx - ci * KK;
      float q = qclip(src[idx], s);
      int ks = ci >> 5, qq = (ci >> 3) & 3, j = ci & 7;
      size_t d = ((((((size_t)(chunk * KK + kk) * NTC + ntl) * KS + ks) * 4 + qq) *
                   16 + mr)) * 8 + j;
      dst[d] = f2bf(q);
    }
  } else if (kind == 3) {
    const int KC = a.KC[t];
    const int nblk = oc >> 6, ntl = (oc >> 4) & 3, mr = oc & 15;
    for (int k = threadIdx.x; k < cik; k += 256) {
      float q = qclip(src[k], s);
      size_t d = ((((((size_t)nblk * KC + (k >> 7)) * 4 + ntl) * 4 + ((k >> 5) & 3)) *
                   4 + ((k >> 3) & 3)) * 16 + mr) * 8 + (k & 7);
      dst[d] = f2bf(q);
    }
  } else {
    for (int k = threadIdx.x; k < cik; k += 256)
      a.dstf[(size_t)oc * cik + k] = qclip(src[k], s) * s;
  }
}

// ------ fold BN (+conv bias, + int-weight scale) into per-channel A,B ------
struct BnArgs {
  const float* p[7][5];   // b, g, be, mu, va
  const float* wsc;
  float* ab;
  int C[7];
  int abo[7];
  int sco[7];
  int cum[8];
};

__global__ __launch_bounds__(256) void bn_all(BnArgs a) {
  int i = blockIdx.x * 256 + threadIdx.x;
  if (i >= a.cum[7]) return;
  int t = 0;
  while (i >= a.cum[t + 1]) t++;
  int c = i - a.cum[t];
  float A = a.p[t][1][c] / sqrtf(a.p[t][4][c] + EPS);
  float B = (a.p[t][0][c] - a.p[t][3][c]) * A + a.p[t][2][c];
  a.ab[a.abo[t] + c] = A * a.wsc[a.sco[t] + c];
  a.ab[a.abo[t] + a.C[t] + c] = B;
}

// ---------------- conv1: MFMA via im2col in LDS (16x16x32) -----------------
__global__ __launch_bounds__(448, 2) void conv1_mfma(
    const float* __restrict__ x, const short* __restrict__ wb1,
    const float* __restrict__ ab, short* __restrict__ out) {
  __shared__ __align__(16) float sx[784];
  __shared__ __align__(16) short sim[784 * 32];
  __shared__ __align__(16) short sw1[1024];
  const int tid = threadIdx.x;
  const int img = blockIdx.x;
  for (int i = tid; i < 784; i += 448) sx[i] = x[(size_t)img * 784 + i];
  for (int i = tid; i < 1024; i += 448) sw1[i] = wb1[i];
  __syncthreads();
  for (int i = tid; i < 25088; i += 448) {
    int p = i >> 5, t = i & 31;
    short v = 0;
    if (t < 25) {
      int py = p / 28, px = p - py * 28;
      int iy = py + t / 5 - 2, ix = px + t % 5 - 2;
      if ((unsigned)iy < 28u && (unsigned)ix < 28u) v = f2bf(sx[iy * 28 + ix]);
    }
    sim[i] = v;
  }
  __syncthreads();
  const int lane = tid & 63, wv = tid >> 6;
  const int mrow = lane & 15, quad = lane >> 4;
  f32x4 acc[7][2];
  #pragma unroll
  for (int i = 0; i < 7; ++i) {
    acc[i][0] = (f32x4){0.f, 0.f, 0.f, 0.f};
    acc[i][1] = (f32x4){0.f, 0.f, 0.f, 0.f};
  }
  #pragma unroll
  for (int i = 0; i < 7; ++i) {
    const int mt = wv * 7 + i;
    const bf16x8 a = *(const bf16x8*)&sim[(mt * 16 + mrow) * 32 + quad * 8];
    #pragma unroll
    for (int nt = 0; nt < 2; ++nt) {
      const bf16x8 b = *(const bf16x8*)&sw1[(nt * 4 + quad) * 128 + mrow * 8];
      acc[i][nt] = __builtin_amdgcn_mfma_f32_16x16x32_bf16(a, b, acc[i][nt], 0, 0, 0);
    }
  }
  #pragma unroll
  for (int i = 0; i < 7; ++i) {
    const int mt = wv * 7 + i;
    #pragma unroll
    for (int nt = 0; nt < 2; ++nt) {
      const int oc = nt * 16 + mrow;
      const float A = ab[oc], Bc = ab[32 + oc];
      #pragma unroll
      for (int r = 0; r < 4; ++r) {
        const int p = mt * 16 + quad * 4 + r;
        float v = fminf(fmaxf(acc[i][nt][r] * A + Bc, -1.f), 1.f);
        out[((size_t)img * 784 + p) * 32 + oc] = f2bf(v);
      }
    }
  }
}

// -------- conv2: half-image blocks, 32x32x16 MFMA, 4 waves, 2 blk/CU --------
// in: h1 [1024][784][32] bf16; wfrag: [25 taps][2 nt][2 ks16][64][8];
// out: h2 [1024][196][64] bf16
__global__ __launch_bounds__(256, 2) void conv2_half(
    const short* __restrict__ in, const short* __restrict__ wfrag,
    const float* __restrict__ ab, short* __restrict__ out) {
  constexpr int S = 4;
  __shared__ __align__(16) short simg[18 * 28 * 32];
  __shared__ __align__(16) short sw[5 * 2048];
  __shared__ __align__(16) short zfrag[8];
  const int tid = threadIdx.x;
  const int img = blockIdx.x >> 1, half = blockIdx.x & 1;
  const int lane = tid & 63, wv = tid >> 6;
  const int l31 = lane & 31, h = lane >> 5;
  if (tid < 8) zfrag[tid] = 0;

  // stage 16 input rows (global rows half*12 .. +15)
  {
    const i32x4* gin = (const i32x4*)(in + ((size_t)img * 784 + half * 12 * 28) * 32);
    const int lyb = half ? 0 : 2;
    for (int c = tid; c < 1792; c += 256) {
      int ps = c >> 2, blk = c & 3;
      int pin_l = (lyb + ps / 28) * 28 + ps % 28;
      ((i32x4*)simg)[pin_l * S + (blk ^ swz(pin_l, 3))] = gin[c];
    }
  }

  int ygl[4], yll[4], xx[4], ppb[4];
  bool uv[4], rv[4];
  #pragma unroll
  for (int i = 0; i < 4; ++i) {
    int u = wv + i * 4;
    uv[i] = u < 13;
    int m = u * 32 + l31;
    int ppl = m >> 2, cd = m & 3;
    rv[i] = uv[i] && (ppl < 98);
    int pr = ppl / 14, pc = ppl - pr * 14;
    ygl[i] = (half * 7 + pr) * 2 + (cd >> 1);
    yll[i] = ygl[i] - (half * 14 - 2);
    xx[i] = pc * 2 + (cd & 1);
    ppb[i] = u * 8;
  }

  f32x16 acc[4][2];
  #pragma unroll
  for (int i = 0; i < 4; ++i)
    #pragma unroll
    for (int nt = 0; nt < 2; ++nt)
      #pragma unroll
      for (int e = 0; e < 16; ++e) acc[i][nt][e] = 0.f;

  for (int tg = 0; tg < 5; ++tg) {
    __syncthreads();
    const i32x4* wsrc = (const i32x4*)(wfrag + tg * 5 * 2048);
    for (int u2 = tid; u2 < 1280; u2 += 256) ((i32x4*)sw)[u2] = wsrc[u2];
    __syncthreads();
    #pragma unroll
    for (int tt = 0; tt < 5; ++tt) {
      const int t = tg * 5 + tt;
      const int dy = t / 5 - 2, dx = t % 5 - 2;
      int aoff[4], sxh[4];
      #pragma unroll
      for (int i = 0; i < 4; ++i) {
        int iy = ygl[i] + dy, ix = xx[i] + dx;
        bool ok = rv[i] && ((unsigned)iy < 28u) && ((unsigned)ix < 28u);
        int pin_l = (yll[i] + dy) * 28 + ix;
        aoff[i] = ok ? pin_l * (S * 8) : -1;
        sxh[i] = swz(pin_l, 3);
      }
      #pragma unroll
      for (int ks = 0; ks < 2; ++ks) {
        bf16x8 af[4];
        #pragma unroll
        for (int i = 0; i < 4; ++i) {
          const short* p = (aoff[i] >= 0)
              ? &simg[aoff[i] + (((ks * 2 + h) ^ sxh[i]) * 8)] : zfrag;
          af[i] = *(const bf16x8*)p;
        }
        #pragma unroll
        for (int nt = 0; nt < 2; ++nt) {
          const bf16x8 bf = *(const bf16x8*)&sw[(((tt * 2 + nt) * 2 + ks) * 64 + lane) * 8];
          #pragma unroll
          for (int i = 0; i < 4; ++i)
            acc[i][nt] = __builtin_amdgcn_mfma_f32_32x32x16_bf16(af[i], bf, acc[i][nt], 0, 0, 0);
        }
      }
    }
  }

  #pragma unroll
  for (int i = 0; i < 4; ++i) {
    #pragma unroll
    for (int nt = 0; nt < 2; ++nt) {
      const int oc = nt * 32 + l31;
      const float A = ab[oc], Bc = ab[64 + oc];
      #pragma unroll
      for (int g = 0; g < 4; ++g) {
        const int ppo = ppb[i] + 2 * g + h;
        if (uv[i] && ppo < 98) {
          float mx = fmaxf(fmaxf(acc[i][nt][g * 4 + 0], acc[i][nt][g * 4 + 1]),
                           fmaxf(acc[i][nt][g * 4 + 2], acc[i][nt][g * 4 + 3]));
          float v = fminf(fmaxf(mx * A + Bc, -1.f), 1.f);
          out[((size_t)img * 196 + half * 98 + ppo) * 64 + oc] = f2bf(v);
        }
      }
    }
  }
}

// -------- conv3: 32x32x16 MFMA, 4 waves, tap-group weights ------------------
template <int CIN, int COUT, int KW, int PAD, int IN_W, int PW, int IMGS,
          int TPI, int MTW, int OCCH, int TG, int WAVES>
__global__ __launch_bounds__(256, 2) void conv23_mfma32(
    const short* __restrict__ in, const short* __restrict__ wfrag,
    const float* __restrict__ ab, short* __restrict__ out) {
  constexpr int S = CIN / 8;
  constexpr int KS16 = CIN / 16;
  constexpr int NT32 = OCCH / 32;
  constexpr int NPIX = IN_W * IN_W;
  constexpr int PP = PW * PW;
  constexpr int KK = KW * KW;
  constexpr int CHUNKS = COUT / OCCH;
  constexpr int NGRP = KK / TG;
  constexpr int WG = TG * NT32 * KS16 * 512;
  constexpr int ITEMS = IMGS * TPI;
  constexpr int INCH = IMGS * NPIX * S;

  __shared__ __align__(16) short simg[IMGS * NPIX * CIN];
  __shared__ __align__(16) short sw[WG];
  __shared__ __align__(16) short zfrag[8];

  const int tid = threadIdx.x;
  const int img0 = blockIdx.x * IMGS;
  const int lane = tid & 63, wv = tid >> 6;
  const int l31 = lane & 31, h = lane >> 5;

  if (tid < 8) zfrag[tid] = 0;

  int yy[MTW], xx[MTW], ibs[MTW], lt_[MTW], il_[MTW];
  bool rv[MTW], uv[MTW];
  #pragma unroll
  for (int i = 0; i < MTW; ++i) {
    int u = wv + i * WAVES;
    uv[i] = u < ITEMS;
    int uu = uv[i] ? u : 0;
    int il = uu / TPI, lt = uu - il * TPI;
    int m = lt * 32 + l31;
    int pp = m >> 2, cd = m & 3;
    rv[i] = uv[i] && (pp < PP);
    int py = pp / PW, px = pp - py * PW;
    yy[i] = py * 2 + (cd >> 1);
    xx[i] = px * 2 + (cd & 1);
    ibs[i] = il * (NPIX * S);
    lt_[i] = lt; il_[i] = il;
  }

  {
    const i32x4* gsrc = (const i32x4*)(in + (size_t)img0 * NPIX * CIN);
    for (int c = tid; c < INCH; c += 256) {
      int il = c / (NPIX * S);
      int r = c - il * (NPIX * S);
      int pix = r / S;
      int blk = r & (S - 1);
      ((i32x4*)simg)[il * (NPIX * S) + pix * S + (blk ^ swz(pix, S - 1))] = gsrc[c];
    }
  }

  for (int ch = 0; ch < CHUNKS; ++ch) {
    f32x16 acc[MTW][NT32];
    #pragma unroll
    for (int i = 0; i < MTW; ++i)
      #pragma unroll
      for (int nt = 0; nt < NT32; ++nt)
        #pragma unroll
        for (int e = 0; e < 16; ++e) acc[i][nt][e] = 0.f;

    for (int tg = 0; tg < NGRP; ++tg) {
      __syncthreads();
      const i32x4* wsrc = (const i32x4*)(wfrag +
          ((size_t)ch * KK + tg * TG) * (NT32 * KS16 * 512));
      for (int u2 = tid; u2 < WG / 8; u2 += 256) ((i32x4*)sw)[u2] = wsrc[u2];
      __syncthreads();

      #pragma unroll
      for (int tt = 0; tt < TG; ++tt) {
        const int t = tg * TG + tt;
        const int dy = t / KW - PAD, dx = t % KW - PAD;
        int aoff[MTW], sxh[MTW];
        #pragma unroll
        for (int i = 0; i < MTW; ++i) {
          int iy = yy[i] + dy, ix = xx[i] + dx;
          bool ok = rv[i] && ((unsigned)iy < (unsigned)IN_W) &&
                    ((unsigned)ix < (unsigned)IN_W);
          int pin = iy * IN_W + ix;
          aoff[i] = ok ? (ibs[i] + pin * S) * 8 : -1;
          sxh[i] = swz(pin, S - 1);
        }
        #pragma unroll
        for (int ks = 0; ks < KS16; ++ks) {
          bf16x8 af[MTW];
          #pragma unroll
          for (int i = 0; i < MTW; ++i) {
            const short* p = (aoff[i] >= 0)
                ? &simg[aoff[i] + (((ks * 2 + h) ^ sxh[i]) * 8)] : zfrag;
            af[i] = *(const bf16x8*)p;
          }
          #pragma unroll
          for (int nt = 0; nt < NT32; ++nt) {
            const bf16x8 bf = *(const bf16x8*)&sw[
                (((tt * NT32 + nt) * KS16 + ks) * 64 + lane) * 8];
            #pragma unroll
            for (int i = 0; i < MTW; ++i)
              acc[i][nt] = __builtin_amdgcn_mfma_f32_32x32x16_bf16(
                  af[i], bf, acc[i][nt], 0, 0, 0);
          }
        }
      }
    }

    #pragma unroll
    for (int i = 0; i < MTW; ++i) {
      #pragma unroll
      for (int nt = 0; nt < NT32; ++nt) {
        const int oc = ch * OCCH + nt * 32 + l31;
        const float A = ab[oc], Bc = ab[COUT + oc];
        #pragma unroll
        for (int g = 0; g < 4; ++g) {
          const int ppo = lt_[i] * 8 + 2 * g + h;
          if (uv[i] && ppo < PP) {
            float mx = fmaxf(fmaxf(acc[i][nt][g * 4 + 0], acc[i][nt][g * 4 + 1]),
                             fmaxf(acc[i][nt][g * 4 + 2], acc[i][nt][g * 4 + 3]));
            float v = fminf(fmaxf(mx * A + Bc, -1.f), 1.f);
            out[((size_t)(img0 + il_[i]) * PP + ppo) * COUT + oc] = f2bf(v);
          }
        }
      }
    }
  }
}

// -------- conv4: tap-outer dbuf weights; emits h4 hi/lo in fc-frag order ----
__global__ __launch_bounds__(512, 2) void conv4_mfma(
    const short* __restrict__ in,      // h3 bf16 [img][49][128]
    const short* __restrict__ wfrag,   // [9][16][4][4][16][8]
    const float* __restrict__ ab,
    short* __restrict__ outH, short* __restrict__ outL) {
  constexpr int S = 16, NPIX = 49, PP = 9;
  __shared__ __align__(16) short simg[2 * NPIX * 128];
  __shared__ __align__(16) short swb[2][32768];
  const int tid = threadIdx.x;
  const int img0 = blockIdx.x * 2;
  const int lane = tid & 63, wv = tid >> 6;
  const int mrow = lane & 15, quad = lane >> 4;

  {
    const i32x4* gsrc = (const i32x4*)(in + (size_t)img0 * NPIX * 128);
    for (int c = tid; c < 2 * NPIX * S; c += 512) {
      int il = c / (NPIX * S);
      int r = c - il * (NPIX * S);
      int pix = r >> 4, blk = r & 15;
      ((i32x4*)simg)[il * NPIX * S + pix * S + (blk ^ (pix & 15))] = gsrc[c];
    }
    for (int u = tid; u < 4096; u += 512)
      ((i32x4*)swb[0])[u] = ((const i32x4*)wfrag)[u];
  }

  int yy[6], xx[6], ibs[6], ppo_[6], ilv[6];
  bool rv[6], pv[6];
  #pragma unroll
  for (int i = 0; i < 6; ++i) {
    int il = i / 3, lt = i - il * 3;
    int m = lt * 16 + mrow;
    int pp = m >> 2, cd = m & 3;
    rv[i] = pp < PP;
    int py = pp / 3, px = pp - py * 3;
    yy[i] = py * 2 + (cd >> 1);
    xx[i] = px * 2 + (cd & 1);
    ibs[i] = il * NPIX * S;
    ilv[i] = il;
    ppo_[i] = lt * 4 + quad;
    pv[i] = ppo_[i] < PP;
  }
  const int nt0 = wv, nt1 = wv + 8;
  f32x4 acc[6][2];
  #pragma unroll
  for (int i = 0; i < 6; ++i) {
    acc[i][0] = (f32x4){0.f, 0.f, 0.f, 0.f};
    acc[i][1] = (f32x4){0.f, 0.f, 0.f, 0.f};
  }
  __syncthreads();

  int dy = -1, dx = -1;
  for (int t = 0; t < 9; ++t) {
    const int buf = t & 1;
    if (t < 8) {
      const i32x4* wsrc = (const i32x4*)(wfrag + (size_t)(t + 1) * 32768);
      for (int u = tid; u < 4096; u += 512) ((i32x4*)swb[buf ^ 1])[u] = wsrc[u];
    }
    #pragma unroll
    for (int ks = 0; ks < 4; ++ks) {
      bf16x8 af[6];
      #pragma unroll
      for (int i = 0; i < 6; ++i) {
        int iy = yy[i] + dy, ix = xx[i] + dx;
        bool ok = rv[i] && (unsigned)iy < 7u && (unsigned)ix < 7u;
        int pin = iy * 7 + ix;
        int blk = (ks * 4 + quad) ^ (pin & 15);
        af[i] = ok ? *(const bf16x8*)&simg[(ibs[i] + pin * S + blk) * 8]
                   : (bf16x8){0, 0, 0, 0, 0, 0, 0, 0};
      }
      const bf16x8 b0 = *(const bf16x8*)&swb[buf][((nt0 * 4 + ks) * 4 + quad) * 128 + mrow * 8];
      const bf16x8 b1 = *(const bf16x8*)&swb[buf][((nt1 * 4 + ks) * 4 + quad) * 128 + mrow * 8];
      #pragma unroll
      for (int i = 0; i < 6; ++i) {
        acc[i][0] = __builtin_amdgcn_mfma_f32_16x16x32_bf16(af[i], b0, acc[i][0], 0, 0, 0);
        acc[i][1] = __builtin_amdgcn_mfma_f32_16x16x32_bf16(af[i], b1, acc[i][1], 0, 0, 0);
      }
    }
    dx++;
    if (dx == 2) { dx = -1; dy++; }
    __syncthreads();
  }

  #pragma unroll
  for (int i = 0; i < 6; ++i) {
    if (pv[i]) {
      #pragma unroll
      for (int nj = 0; nj < 2; ++nj) {
        const int oc = (nj ? nt1 : nt0) * 16 + mrow;
        const f32x4 a = acc[i][nj];
        float mx = fmaxf(fmaxf(a[0], a[1]), fmaxf(a[2], a[3]));
        float v = fminf(fmaxf(mx * ab[oc] + ab[256 + oc], -1.f), 1.f);
        const int m5 = (img0 + ilv[i]) * 9 + ppo_[i];
        size_t d = ((((((size_t)(m5 >> 6) * 2 + (oc >> 7)) * 4 + ((m5 >> 4) & 3)) * 4 +
                     ((oc >> 5) & 3)) * 4 + ((oc >> 3) & 3)) * 16 + (m5 & 15)) * 8 + (oc & 7);
        short hi = f2bf(v);
        outH[d] = hi;
        outL[d] = f2bf(v - bf2f(hi));
      }
    }
  }
}

// ------- fc MFMA GEMM: X hi/lo frag order, int-bf16 W frag order, bn+ht -----
// OUTMODE 0: hi/lo frag for next fc (KC2); 1: fp32 row-major;
// OUTMODE 2: conv5 -> h5 frag (k1 = n*9 + m%9, m1 = m/9, KC2 chunks)
template <int KC, int OUTMODE, int KC2, int NALL>
__global__ __launch_bounds__(256, 2) void fc_mfma(
    const short* __restrict__ Xh, const short* __restrict__ Xl,
    const short* __restrict__ Wf, const float* __restrict__ ab,
    float* __restrict__ outF, short* __restrict__ outH, short* __restrict__ outL) {
  __shared__ __align__(16) short sxh[8192];
  __shared__ __align__(16) short sxl[8192];
  __shared__ __align__(16) short swt[8192];
  const int tid = threadIdx.x;
  const int bn = blockIdx.x, bm = blockIdx.y;
  const int lane = tid & 63, wv = tid >> 6;
  const int mrow = lane & 15, quad = lane >> 4;
  f32x4 acc[4];
  #pragma unroll
  for (int nt = 0; nt < 4; ++nt) acc[nt] = (f32x4){0.f, 0.f, 0.f, 0.f};
  for (int kc = 0; kc < KC; ++kc) {
    __syncthreads();
    {
      const size_t xo = ((size_t)bm * KC + kc) * 8192;
      const size_t wo = ((size_t)bn * KC + kc) * 8192;
      #pragma unroll
      for (int u = 0; u < 4; ++u) {
        ((i32x4*)sxh)[tid + u * 256] = ((const i32x4*)(Xh + xo))[tid + u * 256];
        ((i32x4*)sxl)[tid + u * 256] = ((const i32x4*)(Xl + xo))[tid + u * 256];
        ((i32x4*)swt)[tid + u * 256] = ((const i32x4*)(Wf + wo))[tid + u * 256];
      }
    }
    __syncthreads();
    #pragma unroll
    for (int ks = 0; ks < 4; ++ks) {
      const int ao = (((wv * 4 + ks) * 4 + quad) * 16 + mrow) * 8;
      const bf16x8 ah = *(const bf16x8*)&sxh[ao];
      const bf16x8 al = *(const bf16x8*)&sxl[ao];
      #pragma unroll
      for (int nt = 0; nt < 4; ++nt) {
        const bf16x8 b = *(const bf16x8*)&swt[(((nt * 4 + ks) * 4 + quad) * 16 + mrow) * 8];
        acc[nt] = __builtin_amdgcn_mfma_f32_16x16x32_bf16(ah, b, acc[nt], 0, 0, 0);
        acc[nt] = __builtin_amdgcn_mfma_f32_16x16x32_bf16(al, b, acc[nt], 0, 0, 0);
      }
    }
  }
  #pragma unroll
  for (int nt = 0; nt < 4; ++nt) {
    const int n = bn * 64 + nt * 16 + mrow;
    const float A = ab[n], Bc = ab[NALL + n];
    #pragma unroll
    for (int r = 0; r < 4; ++r) {
      const int m = bm * 64 + wv * 16 + quad * 4 + r;
      float v = fminf(fmaxf(acc[nt][r] * A + Bc, -1.f), 1.f);
      if (OUTMODE == 0) {
        size_t d = (((((((size_t)(m >> 6) * KC2 + (n >> 7)) * 4 + ((m >> 4) & 3)) * 4 +
                       ((n >> 5) & 3)) * 4 + ((n >> 3) & 3)) * 16 + (m & 15))) * 8 + (n & 7);
        short hi = f2bf(v);
        outH[d] = hi;
        outL[d] = f2bf(v - bf2f(hi));
      } else if (OUTMODE == 1) {
        outF[(size_t)m * NALL + n] = v;
      } else {
        const int imgq = m / 9, p = m - imgq * 9;
        const int k1 = n * 9 + p;
        size_t d = ((((((size_t)(imgq >> 6) * KC2 + (k1 >> 7)) * 4 + ((imgq >> 4) & 3)) * 4 +
                     ((k1 >> 5) & 3)) * 4 + ((k1 >> 3) & 3)) * 16 + (imgq & 15)) * 8 + (k1 & 7);
        short hi = f2bf(v);
        outH[d] = hi;
        outL[d] = f2bf(v - bf2f(hi));
      }
    }
  }
}

// ---------------- FC3 ----------------
__global__ __launch_bounds__(256) void fc3_kernel(
    const float* __restrict__ X, const float* __restrict__ W,
    const float* __restrict__ bias, float* __restrict__ out) {
  __shared__ float ws[512 * 10 + 16];
  for (int li = threadIdx.x; li < 5120; li += 256) {
    int n = li / 512, k = li - n * 512;
    ws[k * 10 + n] = W[li];
  }
  __syncthreads();
  const int il = threadIdx.x >> 4, n = threadIdx.x & 15;
  const int img = blockIdx.x * 16 + il;
  if (n < 10) {
    const float* xp = X + (size_t)img * 512;
    float s = 0.f;
    for (int k = 0; k < 512; ++k) s += xp[k] * ws[k * 10 + n];
    out[img * 10 + n] = s + bias[n];
  }
}

// ---------------- launch ----------------
extern "C" void kernel_launch(void* const* d_in, const int* in_sizes, int n_in,
                              void* d_out, int out_size, void* d_ws, size_t ws_size,
                              hipStream_t stream) {
  (void)in_sizes; (void)n_in; (void)out_size; (void)ws_size;
  const float* x = (const float*)d_in[0];
  float* W = (float*)d_ws;

  // workspace layout (floats)
  float* wsc  = W + 0;                       // 2304
  float* ab   = W + 2304;                    // 4608
  float* fq3  = W + 6912;                    // 5120
  short* wb1  = (short*)(W + 12032);         // 1024 sh
  short* wb2  = (short*)(W + 12544);         // 51200 sh
  short* wb3  = (short*)(W + 38144);         // 73728 sh
  short* wb4  = (short*)(W + 75008);         // 294912 sh
  short* wb5  = (short*)(W + 222464);        // 65536 sh
  short* fqb1 = (short*)(W + 255232);        // 2359296 sh
  short* fqb2 = (short*)(W + 1434880);       // 524288 sh
  short* h1   = (short*)(W + 1697024);       // [1024][784][32] bf16 (12845056 fl)
  short* h2   = (short*)(W + 14542080);      // [1024][196][64] bf16 (6422528 fl)
  short* h3   = (short*)(W + 20964608);      // [1024][49][128] bf16 (3211264 fl)
  short* h4h  = (short*)(W + 24175872);      // fc-frag bf16 hi (M=9216,K=256) 1179648 fl
  short* h4l  = (short*)(W + 25355520);      // fc-frag bf16 lo
  short* h5h  = (short*)(W + 26535168);      // fc-frag bf16 hi (M=1024,K=2304) 1179648 fl
  short* h5l  = (short*)(W + 27714816);      // fc-frag bf16 lo
  short* f1h  = (short*)(W + 28894464);      // fc-frag bf16 hi (M=1024,N=1024) 524288 fl
  short* f1l  = (short*)(W + 29418752);      // fc-frag bf16 lo (FIXED stride)
  float* f2   = W + 29943040;                // [1024][512]  (ends 30467328 fl)

  // 1) fused prep: scales + all repacks + fc3 dequant
  PrepArgs pa;
  const int widx[8] = {1, 7, 13, 19, 25, 31, 37, 43};
  short* pdst[8] = {wb1, wb2, wb3, wb4, wb5, fqb1, fqb2, nullptr};
  const int sco8[8] = {0, 32, 96, 224, 480, 736, 1760, 2272};
  const int cik8[8] = {25, 800, 576, 1152, 256, 2304, 1024, 512};
  const int co8[8] = {32, 64, 128, 256, 256, 1024, 512, 10};
  const int kind8[8] = {0, 1, 1, 2, 3, 3, 3, 4};
  const int KK8[8] = {25, 25, 9, 9, 1, 1, 1, 1};
  const int CI8[8] = {1, 32, 64, 128, 256, 2304, 1024, 512};
  const int OCCH8[8] = {32, 64, 64, 256, 256, 1024, 512, 10};
  const int KC8[8] = {1, 1, 1, 1, 2, 18, 8, 1};
  int cum = 0;
  for (int i = 0; i < 8; ++i) {
    pa.w[i] = (const float*)d_in[widx[i]];
    pa.dsth[i] = pdst[i];
    pa.sco[i] = sco8[i];
    pa.cik[i] = cik8[i];
    pa.kind[i] = kind8[i];
    pa.KK[i] = KK8[i];
    pa.CI[i] = CI8[i];
    pa.OCCH[i] = OCCH8[i];
    pa.KC[i] = KC8[i];
    pa.cum[i] = cum;
    cum += co8[i];
  }
  pa.cum[8] = cum;                  // 2282
  pa.dstf = fq3;
  pa.sc = wsc;
  hipLaunchKernelGGL(prep_all, dim3(cum), dim3(256), 0, stream, pa);

  // 2) fold BN (+ int-weight scale, all 7 layers)
  BnArgs ba;
  const int bbase[7] = {2, 8, 14, 20, 26, 32, 38};
  const int bc[7] = {32, 64, 128, 256, 256, 1024, 512};
  const int abo[7] = {0, 64, 192, 448, 960, 1472, 3520};
  int bcum = 0;
  for (int t = 0; t < 7; ++t) {
    for (int j = 0; j < 5; ++j) ba.p[t][j] = (const float*)d_in[bbase[t] + j];
    ba.C[t] = bc[t];
    ba.abo[t] = abo[t];
    ba.sco[t] = sco8[t];
    ba.cum[t] = bcum;
    bcum += bc[t];
  }
  ba.cum[7] = bcum;
  ba.ab = ab;
  ba.wsc = wsc;
  hipLaunchKernelGGL(bn_all, dim3((bcum + 255) / 256), dim3(256), 0, stream, ba);

  // 3) conv stack
  hipLaunchKernelGGL(conv1_mfma, dim3(1024), dim3(448), 0, stream,
                     x, wb1, ab + 0, h1);
  hipLaunchKernelGGL(conv2_half, dim3(2048), dim3(256), 0, stream,
                     h1, wb2, ab + 64, h2);
  hipLaunchKernelGGL((conv23_mfma32<64, 128, 3, 1, 14, 7, 2, 7, 4, 64, 3, 4>),
                     dim3(512), dim3(256), 0, stream, h2, wb3, ab + 192, h3);
  hipLaunchKernelGGL(conv4_mfma, dim3(512), dim3(512), 0, stream,
                     h3, wb4, ab + 448, h4h, h4l);
  hipLaunchKernelGGL((fc_mfma<2, 2, 18, 256>), dim3(4, 144), dim3(256), 0, stream,
                     h4h, h4l, wb5, ab + 960, nullptr, h5h, h5l);

  // 4) FC stack
  hipLaunchKernelGGL((fc_mfma<18, 0, 8, 1024>), dim3(16, 16), dim3(256), 0, stream,
                     h5h, h5l, fqb1, ab + 1472, nullptr, f1h, f1l);
  hipLaunchKernelGGL((fc_mfma<8, 1, 0, 512>), dim3(8, 16), dim3(256), 0, stream,
                     f1h, f1l, fqb2, ab + 3520, f2, nullptr, nullptr);
  hipLaunchKernelGGL(fc3_kernel, dim3(64), dim3(256), 0, stream,
                     f2, fq3, (const float*)d_in[44], (float*)d_out);
}

// Round 7
// 419.298 us; speedup vs baseline: 11.8645x; 1.0413x over previous
//
#include <hip/hip_runtime.h>
#include <hip/hip_bf16.h>
#include <math.h>

// ---------------------------------------------------------------------------
// BinaryCNN round 7:
//  - conv2/conv3: zero-halo padded LDS image (no bounds VALU in K-loop),
//    double-buffered tap-group weights (1 barrier/stage), 2 blk/CU
//  - accumulation order unchanged -> bitwise-identical to R6 output
//  - conv1/conv4/conv5(fc)/fc1/fc2/fc3/prep unchanged from R6 (known good)
// ---------------------------------------------------------------------------

#define EPS 1e-5f

typedef __attribute__((ext_vector_type(8))) short bf16x8;
typedef __attribute__((ext_vector_type(4))) float f32x4;
typedef __attribute__((ext_vector_type(16))) float f32x16;
typedef __attribute__((ext_vector_type(4))) int i32x4;

__device__ __forceinline__ short f2bf(float f) {
  unsigned u = __builtin_bit_cast(unsigned, f);
  unsigned r = u + 0x7FFFu + ((u >> 16) & 1u);   // RNE
  return (short)(r >> 16);
}
__device__ __forceinline__ float bf2f(short h) {
  unsigned u = ((unsigned)(unsigned short)h) << 16;
  return __builtin_bit_cast(float, u);
}
__device__ __forceinline__ int swz(int pin, int smask) {
  return (pin ^ (pin >> 2)) & smask;   // uniform bank-quad spread
}
__device__ __forceinline__ float qclip(float w, float s) {
  return fminf(fmaxf(rintf(w / s), -128.f), 127.f);
}

// ---------------- fused prep: scales + all weight repacks -------------------
struct PrepArgs {
  const float* w[8];
  short* dsth[8];
  float* dstf;
  float* sc;
  int sco[8];
  int cik[8];
  int kind[8];
  int KK[8];
  int CI[8];
  int OCCH[8];
  int KC[8];
  int cum[9];
};

__global__ __launch_bounds__(256) void prep_all(PrepArgs a) {
  int b = blockIdx.x;
  int t = 0;
  while (b >= a.cum[t + 1]) t++;
  int oc = b - a.cum[t];
  int cik = a.cik[t];
  const float* src = a.w[t] + (size_t)oc * cik;
  float m = 0.f;
  for (int i = threadIdx.x; i < cik; i += 256) m = fmaxf(m, fabsf(src[i]));
  #pragma unroll
  for (int o = 1; o < 64; o <<= 1) m = fmaxf(m, __shfl_xor(m, o));
  __shared__ float red[4];
  __shared__ float ssh;
  if ((threadIdx.x & 63) == 0) red[threadIdx.x >> 6] = m;
  __syncthreads();
  if (threadIdx.x == 0) {
    m = fmaxf(fmaxf(red[0], red[1]), fmaxf(red[2], red[3]));
    float s = fmaxf(m / 127.0f, 1e-8f);
    ssh = s;
    a.sc[a.sco[t] + oc] = s;
  }
  __syncthreads();
  const float s = ssh;
  const int kind = a.kind[t];
  short* dst = a.dsth[t];
  if (kind == 0) {
    for (int tt = threadIdx.x; tt < 32; tt += 256) {
      float q = (tt < 25) ? qclip(src[tt], s) : 0.f;
      dst[(((oc >> 4) * 4 + (tt >> 3)) * 16 + (oc & 15)) * 8 + (tt & 7)] = f2bf(q);
    }
  } else if (kind == 1) {
    const int KK = a.KK[t], CI = a.CI[t], OCCH = a.OCCH[t];
    const int NT32 = OCCH >> 5, KS16 = CI >> 4;
    const int chunk = oc / OCCH, ocl = oc - chunk * OCCH;
    const int nt = ocl >> 5, n32 = ocl & 31;
    for (int idx = threadIdx.x; idx < cik; idx += 256) {
      int ci = idx / KK, kk = idx - ci * KK;
      float q = qclip(src[idx], s);
      int ks = ci >> 4, hh = (ci >> 3) & 1, j = ci & 7;
      size_t d = ((((size_t)(chunk * KK + kk) * NT32 + nt) * KS16 + ks) * 64 +
                  hh * 32 + n32) * 8 + j;
      dst[d] = f2bf(q);
    }
  } else if (kind == 2) {
    const int KK = a.KK[t], CI = a.CI[t], OCCH = a.OCCH[t];
    const int NTC = OCCH >> 4, KS = CI >> 5;
    const int chunk = oc / OCCH, ocl = oc - chunk * OCCH;
    const int ntl = ocl >> 4, mr = ocl & 15;
    for (int idx = threadIdx.x; idx < cik; idx += 256) {
      int ci = idx / KK, kk = idx - ci * KK;
      float q = qclip(src[idx], s);
      int ks = ci >> 5, qq = (ci >> 3) & 3, j = ci & 7;
      size_t d = ((((((size_t)(chunk * KK + kk) * NTC + ntl) * KS + ks) * 4 + qq) *
                   16 + mr)) * 8 + j;
      dst[d] = f2bf(q);
    }
  } else if (kind == 3) {
    const int KC = a.KC[t];
    const int nblk = oc >> 6, ntl = (oc >> 4) & 3, mr = oc & 15;
    for (int k = threadIdx.x; k < cik; k += 256) {
      float q = qclip(src[k], s);
      size_t d = ((((((size_t)nblk * KC + (k >> 7)) * 4 + ntl) * 4 + ((k >> 5) & 3)) *
                   4 + ((k >> 3) & 3)) * 16 + mr) * 8 + (k & 7);
      dst[d] = f2bf(q);
    }
  } else {
    for (int k = threadIdx.x; k < cik; k += 256)
      a.dstf[(size_t)oc * cik + k] = qclip(src[k], s) * s;
  }
}

// ------ fold BN (+conv bias, + int-weight scale) into per-channel A,B ------
struct BnArgs {
  const float* p[7][5];   // b, g, be, mu, va
  const float* wsc;
  float* ab;
  int C[7];
  int abo[7];
  int sco[7];
  int cum[8];
};

__global__ __launch_bounds__(256) void bn_all(BnArgs a) {
  int i = blockIdx.x * 256 + threadIdx.x;
  if (i >= a.cum[7]) return;
  int t = 0;
  while (i >= a.cum[t + 1]) t++;
  int c = i - a.cum[t];
  float A = a.p[t][1][c] / sqrtf(a.p[t][4][c] + EPS);
  float B = (a.p[t][0][c] - a.p[t][3][c]) * A + a.p[t][2][c];
  a.ab[a.abo[t] + c] = A * a.wsc[a.sco[t] + c];
  a.ab[a.abo[t] + a.C[t] + c] = B;
}

// ---------------- conv1: MFMA via im2col in LDS (16x16x32) -----------------
__global__ __launch_bounds__(448, 2) void conv1_mfma(
    const float* __restrict__ x, const short* __restrict__ wb1,
    const float* __restrict__ ab, short* __restrict__ out) {
  __shared__ __align__(16) float sx[784];
  __shared__ __align__(16) short sim[784 * 32];
  __shared__ __align__(16) short sw1[1024];
  const int tid = threadIdx.x;
  const int img = blockIdx.x;
  for (int i = tid; i < 784; i += 448) sx[i] = x[(size_t)img * 784 + i];
  for (int i = tid; i < 1024; i += 448) sw1[i] = wb1[i];
  __syncthreads();
  for (int i = tid; i < 25088; i += 448) {
    int p = i >> 5, t = i & 31;
    short v = 0;
    if (t < 25) {
      int py = p / 28, px = p - py * 28;
      int iy = py + t / 5 - 2, ix = px + t % 5 - 2;
      if ((unsigned)iy < 28u && (unsigned)ix < 28u) v = f2bf(sx[iy * 28 + ix]);
    }
    sim[i] = v;
  }
  __syncthreads();
  const int lane = tid & 63, wv = tid >> 6;
  const int mrow = lane & 15, quad = lane >> 4;
  f32x4 acc[7][2];
  #pragma unroll
  for (int i = 0; i < 7; ++i) {
    acc[i][0] = (f32x4){0.f, 0.f, 0.f, 0.f};
    acc[i][1] = (f32x4){0.f, 0.f, 0.f, 0.f};
  }
  #pragma unroll
  for (int i = 0; i < 7; ++i) {
    const int mt = wv * 7 + i;
    const bf16x8 a = *(const bf16x8*)&sim[(mt * 16 + mrow) * 32 + quad * 8];
    #pragma unroll
    for (int nt = 0; nt < 2; ++nt) {
      const bf16x8 b = *(const bf16x8*)&sw1[(nt * 4 + quad) * 128 + mrow * 8];
      acc[i][nt] = __builtin_amdgcn_mfma_f32_16x16x32_bf16(a, b, acc[i][nt], 0, 0, 0);
    }
  }
  #pragma unroll
  for (int i = 0; i < 7; ++i) {
    const int mt = wv * 7 + i;
    #pragma unroll
    for (int nt = 0; nt < 2; ++nt) {
      const int oc = nt * 16 + mrow;
      const float A = ab[oc], Bc = ab[32 + oc];
      #pragma unroll
      for (int r = 0; r < 4; ++r) {
        const int p = mt * 16 + quad * 4 + r;
        float v = fminf(fmaxf(acc[i][nt][r] * A + Bc, -1.f), 1.f);
        out[((size_t)img * 784 + p) * 32 + oc] = f2bf(v);
      }
    }
  }
}

// -------- conv2: half-image, zero-halo padded LDS, dbuf weights -------------
// in: h1 [1024][784][32] bf16; wfrag: [25 taps][2 nt][2 ks16][64][8];
// out: h2 [1024][196][64] bf16
__global__ __launch_bounds__(256, 2) void conv2_half(
    const short* __restrict__ in, const short* __restrict__ wfrag,
    const float* __restrict__ ab, short* __restrict__ out) {
  constexpr int S = 4;                 // 16B blocks per pixel (32 ch)
  constexpr int RS = 32;               // padded row stride (cols)
  __shared__ __align__(16) short simg[18 * 32 * 32];   // 36864 B
  __shared__ __align__(16) short sw[2][10240];          // 2 x 20 KB
  const int tid = threadIdx.x;
  const int img = blockIdx.x >> 1, half = blockIdx.x & 1;
  const int lane = tid & 63, wv = tid >> 6;
  const int l31 = lane & 31, h = lane >> 5;

  // zero halo: 2 pad rows (full) + 4 pad cols x 16 valid rows = 128 px
  {
    const int padrow0 = half ? 16 : 0;
    const int vrow0 = half ? 0 : 2;
    for (int c = tid; c < 512; c += 256) {
      int hp = c >> 2, blk = c & 3;
      int pin;
      if (hp < 64) {
        pin = (padrow0 + (hp >> 5)) * RS + (hp & 31);
      } else {
        int r = (hp - 64) >> 2, cc = (hp - 64) & 3;
        int col = (cc < 2) ? cc : (28 + cc);
        pin = (vrow0 + r) * RS + col;
      }
      ((i32x4*)simg)[pin * S + blk] = (i32x4){0, 0, 0, 0};
    }
  }
  // stage 16 valid rows (global rows half*12 .. +15) at local rows vrow0..
  {
    const i32x4* gin = (const i32x4*)(in + ((size_t)img * 784 + half * 12 * 28) * 32);
    const int vrow0 = half ? 0 : 2;
    for (int c = tid; c < 1792; c += 256) {
      int ps = c >> 2, blk = c & 3;
      int pin = (vrow0 + ps / 28) * RS + ps % 28 + 2;
      ((i32x4*)simg)[pin * S + (blk ^ swz(pin, 3))] = gin[c];
    }
  }

  // tile geometry: u-th m-tile (32 rows), lane row l31
  int pinb[4], ppb[4];
  bool uv2[4];
  #pragma unroll
  for (int i = 0; i < 4; ++i) {
    int u = wv + i * 4;
    uv2[i] = u < 13;
    int m = u * 32 + l31;
    int ppl = m >> 2, cd = m & 3;
    bool ok = uv2[i] && (ppl < 98);
    int pr = ppl / 14, pc = ppl - pr * 14;
    int ygl = (half * 7 + pr) * 2 + (cd >> 1);        // global y (dy=0)
    int yll = ygl - (half * 14 - 2);                  // local row in [2,15]
    int xc = pc * 2 + (cd & 1) + 2;                   // local col in [2,29]
    pinb[i] = ok ? (yll * RS + xc) : (2 * RS + 2);    // safe center if masked
    ppb[i] = u * 8;
  }

  f32x16 acc[4][2];
  #pragma unroll
  for (int i = 0; i < 4; ++i)
    #pragma unroll
    for (int nt = 0; nt < 2; ++nt)
      #pragma unroll
      for (int e = 0; e < 16; ++e) acc[i][nt][e] = 0.f;

  // weight pipeline: 5 groups of 5 taps, 1280 i32x4 per group (5/thread)
  i32x4 wreg[5];
  {
    const i32x4* ws0 = (const i32x4*)wfrag;
    #pragma unroll
    for (int u2 = 0; u2 < 5; ++u2) wreg[u2] = ws0[tid + u2 * 256];
    #pragma unroll
    for (int u2 = 0; u2 < 5; ++u2) ((i32x4*)sw[0])[tid + u2 * 256] = wreg[u2];
  }

  for (int tg = 0; tg < 5; ++tg) {
    __syncthreads();
    if (tg < 4) {
      const i32x4* ws = (const i32x4*)(wfrag + (size_t)(tg + 1) * 10240);
      #pragma unroll
      for (int u2 = 0; u2 < 5; ++u2) wreg[u2] = ws[tid + u2 * 256];
    }
    const short* swb = sw[tg & 1];
    const int dy = tg - 2;
    #pragma unroll
    for (int tt = 0; tt < 5; ++tt) {
      const int tp = dy * RS + (tt - 2);
      int pin[4], sx4[4];
      #pragma unroll
      for (int i = 0; i < 4; ++i) {
        pin[i] = pinb[i] + tp;
        sx4[i] = swz(pin[i], 3);
      }
      #pragma unroll
      for (int ks = 0; ks < 2; ++ks) {
        bf16x8 af[4];
        #pragma unroll
        for (int i = 0; i < 4; ++i)
          af[i] = *(const bf16x8*)&simg[pin[i] * 32 + (((ks * 2 + h) ^ sx4[i]) * 8)];
        #pragma unroll
        for (int nt = 0; nt < 2; ++nt) {
          const bf16x8 bf = *(const bf16x8*)&swb[(((tt * 2 + nt) * 2 + ks) * 64 + lane) * 8];
          #pragma unroll
          for (int i = 0; i < 4; ++i)
            acc[i][nt] = __builtin_amdgcn_mfma_f32_32x32x16_bf16(af[i], bf, acc[i][nt], 0, 0, 0);
        }
      }
    }
    if (tg < 4) {
      #pragma unroll
      for (int u2 = 0; u2 < 5; ++u2)
        ((i32x4*)sw[(tg + 1) & 1])[tid + u2 * 256] = wreg[u2];
    }
  }

  #pragma unroll
  for (int i = 0; i < 4; ++i) {
    #pragma unroll
    for (int nt = 0; nt < 2; ++nt) {
      const int oc = nt * 32 + l31;
      const float A = ab[oc], Bc = ab[64 + oc];
      #pragma unroll
      for (int g = 0; g < 4; ++g) {
        const int ppo = ppb[i] + 2 * g + h;
        if (uv2[i] && ppo < 98) {
          float mx = fmaxf(fmaxf(acc[i][nt][g * 4 + 0], acc[i][nt][g * 4 + 1]),
                           fmaxf(acc[i][nt][g * 4 + 2], acc[i][nt][g * 4 + 3]));
          float v = fminf(fmaxf(mx * A + Bc, -1.f), 1.f);
          out[((size_t)img * 196 + half * 98 + ppo) * 64 + oc] = f2bf(v);
        }
      }
    }
  }
}

// -------- conv3: 2 imgs, zero-halo 16x16 padded LDS, dbuf per-tap weights ---
// in: h2 [1024][196][64] bf16; wfrag: [2ch][9kk][2nt][4ks][64][8];
// out: h3 [1024][49][128] bf16
__global__ __launch_bounds__(256, 2) void conv3_pad(
    const short* __restrict__ in, const short* __restrict__ wfrag,
    const float* __restrict__ ab, short* __restrict__ out) {
  constexpr int S = 8, RS = 16;
  __shared__ __align__(16) short simg[2 * 256 * 64];    // 65536 B
  __shared__ __align__(16) short sw[2][4096];           // 2 x 8 KB
  const int tid = threadIdx.x;
  const int img0 = blockIdx.x * 2;
  const int lane = tid & 63, wv = tid >> 6;
  const int l31 = lane & 31, h = lane >> 5;

  // zero halo: 60 px/img (rows 0,15 full; cols 0,15 of rows 1..14)
  for (int c = tid; c < 960; c += 256) {
    int blk = c & 7, hp0 = c >> 3;
    int il = hp0 >= 60 ? 1 : 0, hp = hp0 - il * 60;
    int pin;
    if (hp < 32) pin = (hp >> 4) * 15 * RS + (hp & 15);
    else {
      int r = ((hp - 32) >> 1) + 1, cc = ((hp - 32) & 1) * 15;
      pin = r * RS + cc;
    }
    ((i32x4*)simg)[(il * 256 + pin) * S + blk] = (i32x4){0, 0, 0, 0};
  }
  // stage 2 x 196 px
  {
    const i32x4* gin = (const i32x4*)(in + (size_t)img0 * 196 * 64);
    for (int c = tid; c < 3136; c += 256) {
      int il = c / 1568, r = c - il * 1568;
      int ps = r >> 3, blk = r & 7;
      int pin = (ps / 14 + 1) * RS + ps % 14 + 1;
      ((i32x4*)simg)[(il * 256 + pin) * S + (blk ^ swz(pin, 7))] = gin[c];
    }
  }

  // tile geometry (14 items = 2 imgs x 7 m-tiles)
  int pinb[4], ppb[4], ilv[4];
  bool uv4[4];
  #pragma unroll
  for (int i = 0; i < 4; ++i) {
    int u = wv + i * 4;
    uv4[i] = u < 14;
    int uu = uv4[i] ? u : 0;
    int il = uu / 7, lt = uu - il * 7;
    int m = lt * 32 + l31, ppl = m >> 2, cd = m & 3;
    bool ok = uv4[i] && (ppl < 49);
    int py = ppl / 7, px = ppl - py * 7;
    int y = py * 2 + (cd >> 1), x = px * 2 + (cd & 1);
    pinb[i] = (ok ? ((y + 1) * RS + x + 1) : (RS + 1)) + il * 256;
    ilv[i] = il;
    ppb[i] = lt * 8;
  }

  f32x16 acc[4][2];
  #pragma unroll
  for (int i = 0; i < 4; ++i)
    #pragma unroll
    for (int nt = 0; nt < 2; ++nt)
      #pragma unroll
      for (int e = 0; e < 16; ++e) acc[i][nt][e] = 0.f;

  // weight pipeline: 18 stages (2 chunks x 9 taps), 512 i32x4/stage (2/thread)
  i32x4 wreg[2];
  {
    const i32x4* ws0 = (const i32x4*)wfrag;
    wreg[0] = ws0[tid];
    wreg[1] = ws0[tid + 256];
    ((i32x4*)sw[0])[tid] = wreg[0];
    ((i32x4*)sw[0])[tid + 256] = wreg[1];
  }

  for (int s = 0; s < 18; ++s) {
    __syncthreads();
    if (s < 17) {
      const i32x4* ws = (const i32x4*)(wfrag + (size_t)(s + 1) * 4096);
      wreg[0] = ws[tid];
      wreg[1] = ws[tid + 256];
    }
    const short* swb = sw[s & 1];
    const int t = s % 9;
    const int tp = (t / 3 - 1) * RS + (t % 3 - 1);
    int pin[4], sx4[4];
    #pragma unroll
    for (int i = 0; i < 4; ++i) {
      pin[i] = pinb[i] + tp;
      sx4[i] = swz(pin[i], 7);
    }
    #pragma unroll
    for (int ks = 0; ks < 4; ++ks) {
      bf16x8 af[4];
      #pragma unroll
      for (int i = 0; i < 4; ++i)
        af[i] = *(const bf16x8*)&simg[pin[i] * 64 + (((ks * 2 + h) ^ sx4[i]) * 8)];
      #pragma unroll
      for (int nt = 0; nt < 2; ++nt) {
        const bf16x8 bf = *(const bf16x8*)&swb[((nt * 4 + ks) * 64 + lane) * 8];
        #pragma unroll
        for (int i = 0; i < 4; ++i)
          acc[i][nt] = __builtin_amdgcn_mfma_f32_32x32x16_bf16(af[i], bf, acc[i][nt], 0, 0, 0);
      }
    }
    if (s < 17) {
      ((i32x4*)sw[(s + 1) & 1])[tid] = wreg[0];
      ((i32x4*)sw[(s + 1) & 1])[tid + 256] = wreg[1];
    }
    if (t == 8) {
      const int ch = s / 9;
      #pragma unroll
      for (int i = 0; i < 4; ++i) {
        #pragma unroll
        for (int nt = 0; nt < 2; ++nt) {
          const int oc = ch * 64 + nt * 32 + l31;
          const float A = ab[oc], Bc = ab[128 + oc];
          #pragma unroll
          for (int g = 0; g < 4; ++g) {
            const int ppo = ppb[i] + 2 * g + h;
            if (uv4[i] && ppo < 49) {
              float mx = fmaxf(fmaxf(acc[i][nt][g * 4 + 0], acc[i][nt][g * 4 + 1]),
                               fmaxf(acc[i][nt][g * 4 + 2], acc[i][nt][g * 4 + 3]));
              float v = fminf(fmaxf(mx * A + Bc, -1.f), 1.f);
              out[((size_t)(img0 + ilv[i]) * 49 + ppo) * 128 + oc] = f2bf(v);
            }
          }
          #pragma unroll
          for (int e = 0; e < 16; ++e) acc[i][nt][e] = 0.f;
        }
      }
    }
  }
}

// -------- conv4: tap-outer dbuf weights; emits h4 hi/lo in fc-frag order ----
__global__ __launch_bounds__(512, 2) void conv4_mfma(
    const short* __restrict__ in,      // h3 bf16 [img][49][128]
    const short* __restrict__ wfrag,   // [9][16][4][4][16][8]
    const float* __restrict__ ab,
    short* __restrict__ outH, short* __restrict__ outL) {
  constexpr int S = 16, NPIX = 49, PP = 9;
  __shared__ __align__(16) short simg[2 * NPIX * 128];
  __shared__ __align__(16) short swb[2][32768];
  const int tid = threadIdx.x;
  const int img0 = blockIdx.x * 2;
  const int lane = tid & 63, wv = tid >> 6;
  const int mrow = lane & 15, quad = lane >> 4;

  {
    const i32x4* gsrc = (const i32x4*)(in + (size_t)img0 * NPIX * 128);
    for (int c = tid; c < 2 * NPIX * S; c += 512) {
      int il = c / (NPIX * S);
      int r = c - il * (NPIX * S);
      int pix = r >> 4, blk = r & 15;
      ((i32x4*)simg)[il * NPIX * S + pix * S + (blk ^ (pix & 15))] = gsrc[c];
    }
    for (int u = tid; u < 4096; u += 512)
      ((i32x4*)swb[0])[u] = ((const i32x4*)wfrag)[u];
  }

  int yy[6], xx[6], ibs[6], ppo_[6], ilv[6];
  bool rv[6], pv[6];
  #pragma unroll
  for (int i = 0; i < 6; ++i) {
    int il = i / 3, lt = i - il * 3;
    int m = lt * 16 + mrow;
    int pp = m >> 2, cd = m & 3;
    rv[i] = pp < PP;
    int py = pp / 3, px = pp - py * 3;
    yy[i] = py * 2 + (cd >> 1);
    xx[i] = px * 2 + (cd & 1);
    ibs[i] = il * NPIX * S;
    ilv[i] = il;
    ppo_[i] = lt * 4 + quad;
    pv[i] = ppo_[i] < PP;
  }
  const int nt0 = wv, nt1 = wv + 8;
  f32x4 acc[6][2];
  #pragma unroll
  for (int i = 0; i < 6; ++i) {
    acc[i][0] = (f32x4){0.f, 0.f, 0.f, 0.f};
    acc[i][1] = (f32x4){0.f, 0.f, 0.f, 0.f};
  }
  __syncthreads();

  int dy = -1, dx = -1;
  for (int t = 0; t < 9; ++t) {
    const int buf = t & 1;
    if (t < 8) {
      const i32x4* wsrc = (const i32x4*)(wfrag + (size_t)(t + 1) * 32768);
      for (int u = tid; u < 4096; u += 512) ((i32x4*)swb[buf ^ 1])[u] = wsrc[u];
    }
    #pragma unroll
    for (int ks = 0; ks < 4; ++ks) {
      bf16x8 af[6];
      #pragma unroll
      for (int i = 0; i < 6; ++i) {
        int iy = yy[i] + dy, ix = xx[i] + dx;
        bool ok = rv[i] && (unsigned)iy < 7u && (unsigned)ix < 7u;
        int pin = iy * 7 + ix;
        int blk = (ks * 4 + quad) ^ (pin & 15);
        af[i] = ok ? *(const bf16x8*)&simg[(ibs[i] + pin * S + blk) * 8]
                   : (bf16x8){0, 0, 0, 0, 0, 0, 0, 0};
      }
      const bf16x8 b0 = *(const bf16x8*)&swb[buf][((nt0 * 4 + ks) * 4 + quad) * 128 + mrow * 8];
      const bf16x8 b1 = *(const bf16x8*)&swb[buf][((nt1 * 4 + ks) * 4 + quad) * 128 + mrow * 8];
      #pragma unroll
      for (int i = 0; i < 6; ++i) {
        acc[i][0] = __builtin_amdgcn_mfma_f32_16x16x32_bf16(af[i], b0, acc[i][0], 0, 0, 0);
        acc[i][1] = __builtin_amdgcn_mfma_f32_16x16x32_bf16(af[i], b1, acc[i][1], 0, 0, 0);
      }
    }
    dx++;
    if (dx == 2) { dx = -1; dy++; }
    __syncthreads();
  }

  #pragma unroll
  for (int i = 0; i < 6; ++i) {
    if (pv[i]) {
      #pragma unroll
      for (int nj = 0; nj < 2; ++nj) {
        const int oc = (nj ? nt1 : nt0) * 16 + mrow;
        const f32x4 a = acc[i][nj];
        float mx = fmaxf(fmaxf(a[0], a[1]), fmaxf(a[2], a[3]));
        float v = fminf(fmaxf(mx * ab[oc] + ab[256 + oc], -1.f), 1.f);
        const int m5 = (img0 + ilv[i]) * 9 + ppo_[i];
        size_t d = ((((((size_t)(m5 >> 6) * 2 + (oc >> 7)) * 4 + ((m5 >> 4) & 3)) * 4 +
                     ((oc >> 5) & 3)) * 4 + ((oc >> 3) & 3)) * 16 + (m5 & 15)) * 8 + (oc & 7);
        short hi = f2bf(v);
        outH[d] = hi;
        outL[d] = f2bf(v - bf2f(hi));
      }
    }
  }
}

// ------- fc MFMA GEMM: X hi/lo frag order, int-bf16 W frag order, bn+ht -----
// OUTMODE 0: hi/lo frag for next fc (KC2); 1: fp32 row-major;
// OUTMODE 2: conv5 -> h5 frag (k1 = n*9 + m%9, m1 = m/9, KC2 chunks)
template <int KC, int OUTMODE, int KC2, int NALL>
__global__ __launch_bounds__(256, 2) void fc_mfma(
    const short* __restrict__ Xh, const short* __restrict__ Xl,
    const short* __restrict__ Wf, const float* __restrict__ ab,
    float* __restrict__ outF, short* __restrict__ outH, short* __restrict__ outL) {
  __shared__ __align__(16) short sxh[8192];
  __shared__ __align__(16) short sxl[8192];
  __shared__ __align__(16) short swt[8192];
  const int tid = threadIdx.x;
  const int bn = blockIdx.x, bm = blockIdx.y;
  const int lane = tid & 63, wv = tid >> 6;
  const int mrow = lane & 15, quad = lane >> 4;
  f32x4 acc[4];
  #pragma unroll
  for (int nt = 0; nt < 4; ++nt) acc[nt] = (f32x4){0.f, 0.f, 0.f, 0.f};
  for (int kc = 0; kc < KC; ++kc) {
    __syncthreads();
    {
      const size_t xo = ((size_t)bm * KC + kc) * 8192;
      const size_t wo = ((size_t)bn * KC + kc) * 8192;
      #pragma unroll
      for (int u = 0; u < 4; ++u) {
        ((i32x4*)sxh)[tid + u * 256] = ((const i32x4*)(Xh + xo))[tid + u * 256];
        ((i32x4*)sxl)[tid + u * 256] = ((const i32x4*)(Xl + xo))[tid + u * 256];
        ((i32x4*)swt)[tid + u * 256] = ((const i32x4*)(Wf + wo))[tid + u * 256];
      }
    }
    __syncthreads();
    #pragma unroll
    for (int ks = 0; ks < 4; ++ks) {
      const int ao = (((wv * 4 + ks) * 4 + quad) * 16 + mrow) * 8;
      const bf16x8 ah = *(const bf16x8*)&sxh[ao];
      const bf16x8 al = *(const bf16x8*)&sxl[ao];
      #pragma unroll
      for (int nt = 0; nt < 4; ++nt) {
        const bf16x8 b = *(const bf16x8*)&swt[(((nt * 4 + ks) * 4 + quad) * 16 + mrow) * 8];
        acc[nt] = __builtin_amdgcn_mfma_f32_16x16x32_bf16(ah, b, acc[nt], 0, 0, 0);
        acc[nt] = __builtin_amdgcn_mfma_f32_16x16x32_bf16(al, b, acc[nt], 0, 0, 0);
      }
    }
  }
  #pragma unroll
  for (int nt = 0; nt < 4; ++nt) {
    const int n = bn * 64 + nt * 16 + mrow;
    const float A = ab[n], Bc = ab[NALL + n];
    #pragma unroll
    for (int r = 0; r < 4; ++r) {
      const int m = bm * 64 + wv * 16 + quad * 4 + r;
      float v = fminf(fmaxf(acc[nt][r] * A + Bc, -1.f), 1.f);
      if (OUTMODE == 0) {
        size_t d = (((((((size_t)(m >> 6) * KC2 + (n >> 7)) * 4 + ((m >> 4) & 3)) * 4 +
                       ((n >> 5) & 3)) * 4 + ((n >> 3) & 3)) * 16 + (m & 15))) * 8 + (n & 7);
        short hi = f2bf(v);
        outH[d] = hi;
        outL[d] = f2bf(v - bf2f(hi));
      } else if (OUTMODE == 1) {
        outF[(size_t)m * NALL + n] = v;
      } else {
        const int imgq = m / 9, p = m - imgq * 9;
        const int k1 = n * 9 + p;
        size_t d = ((((((size_t)(imgq >> 6) * KC2 + (k1 >> 7)) * 4 + ((imgq >> 4) & 3)) * 4 +
                     ((k1 >> 5) & 3)) * 4 + ((k1 >> 3) & 3)) * 16 + (imgq & 15)) * 8 + (k1 & 7);
        short hi = f2bf(v);
        outH[d] = hi;
        outL[d] = f2bf(v - bf2f(hi));
      }
    }
  }
}

// ---------------- FC3 ----------------
__global__ __launch_bounds__(256) void fc3_kernel(
    const float* __restrict__ X, const float* __restrict__ W,
    const float* __restrict__ bias, float* __restrict__ out) {
  __shared__ float ws[512 * 10 + 16];
  for (int li = threadIdx.x; li < 5120; li += 256) {
    int n = li / 512, k = li - n * 512;
    ws[k * 10 + n] = W[li];
  }
  __syncthreads();
  const int il = threadIdx.x >> 4, n = threadIdx.x & 15;
  const int img = blockIdx.x * 16 + il;
  if (n < 10) {
    const float* xp = X + (size_t)img * 512;
    float s = 0.f;
    for (int k = 0; k < 512; ++k) s += xp[k] * ws[k * 10 + n];
    out[img * 10 + n] = s + bias[n];
  }
}

// ---------------- launch ----------------
extern "C" void kernel_launch(void* const* d_in, const int* in_sizes, int n_in,
                              void* d_out, int out_size, void* d_ws, size_t ws_size,
                              hipStream_t stream) {
  (void)in_sizes; (void)n_in; (void)out_size; (void)ws_size;
  const float* x = (const float*)d_in[0];
  float* W = (float*)d_ws;

  // workspace layout (floats)
  float* wsc  = W + 0;                       // 2304
  float* ab   = W + 2304;                    // 4608
  float* fq3  = W + 6912;                    // 5120
  short* wb1  = (short*)(W + 12032);         // 1024 sh
  short* wb2  = (short*)(W + 12544);         // 51200 sh
  short* wb3  = (short*)(W + 38144);         // 73728 sh
  short* wb4  = (short*)(W + 75008);         // 294912 sh
  short* wb5  = (short*)(W + 222464);        // 65536 sh
  short* fqb1 = (short*)(W + 255232);        // 2359296 sh
  short* fqb2 = (short*)(W + 1434880);       // 524288 sh
  short* h1   = (short*)(W + 1697024);       // [1024][784][32] bf16
  short* h2   = (short*)(W + 14542080);      // [1024][196][64] bf16
  short* h3   = (short*)(W + 20964608);      // [1024][49][128] bf16
  short* h4h  = (short*)(W + 24175872);      // fc-frag bf16 hi (M=9216,K=256)
  short* h4l  = (short*)(W + 25355520);      // fc-frag bf16 lo
  short* h5h  = (short*)(W + 26535168);      // fc-frag bf16 hi (M=1024,K=2304)
  short* h5l  = (short*)(W + 27714816);      // fc-frag bf16 lo
  short* f1h  = (short*)(W + 28894464);      // fc-frag bf16 hi (M=1024,N=1024)
  short* f1l  = (short*)(W + 29418752);      // fc-frag bf16 lo
  float* f2   = W + 29943040;                // [1024][512]

  // 1) fused prep: scales + all repacks + fc3 dequant
  PrepArgs pa;
  const int widx[8] = {1, 7, 13, 19, 25, 31, 37, 43};
  short* pdst[8] = {wb1, wb2, wb3, wb4, wb5, fqb1, fqb2, nullptr};
  const int sco8[8] = {0, 32, 96, 224, 480, 736, 1760, 2272};
  const int cik8[8] = {25, 800, 576, 1152, 256, 2304, 1024, 512};
  const int co8[8] = {32, 64, 128, 256, 256, 1024, 512, 10};
  const int kind8[8] = {0, 1, 1, 2, 3, 3, 3, 4};
  const int KK8[8] = {25, 25, 9, 9, 1, 1, 1, 1};
  const int CI8[8] = {1, 32, 64, 128, 256, 2304, 1024, 512};
  const int OCCH8[8] = {32, 64, 64, 256, 256, 1024, 512, 10};
  const int KC8[8] = {1, 1, 1, 1, 2, 18, 8, 1};
  int cum = 0;
  for (int i = 0; i < 8; ++i) {
    pa.w[i] = (const float*)d_in[widx[i]];
    pa.dsth[i] = pdst[i];
    pa.sco[i] = sco8[i];
    pa.cik[i] = cik8[i];
    pa.kind[i] = kind8[i];
    pa.KK[i] = KK8[i];
    pa.CI[i] = CI8[i];
    pa.OCCH[i] = OCCH8[i];
    pa.KC[i] = KC8[i];
    pa.cum[i] = cum;
    cum += co8[i];
  }
  pa.cum[8] = cum;                  // 2282
  pa.dstf = fq3;
  pa.sc = wsc;
  hipLaunchKernelGGL(prep_all, dim3(cum), dim3(256), 0, stream, pa);

  // 2) fold BN (+ int-weight scale, all 7 layers)
  BnArgs ba;
  const int bbase[7] = {2, 8, 14, 20, 26, 32, 38};
  const int bc[7] = {32, 64, 128, 256, 256, 1024, 512};
  const int abo[7] = {0, 64, 192, 448, 960, 1472, 3520};
  int bcum = 0;
  for (int t = 0; t < 7; ++t) {
    for (int j = 0; j < 5; ++j) ba.p[t][j] = (const float*)d_in[bbase[t] + j];
    ba.C[t] = bc[t];
    ba.abo[t] = abo[t];
    ba.sco[t] = sco8[t];
    ba.cum[t] = bcum;
    bcum += bc[t];
  }
  ba.cum[7] = bcum;
  ba.ab = ab;
  ba.wsc = wsc;
  hipLaunchKernelGGL(bn_all, dim3((bcum + 255) / 256), dim3(256), 0, stream, ba);

  // 3) conv stack
  hipLaunchKernelGGL(conv1_mfma, dim3(1024), dim3(448), 0, stream,
                     x, wb1, ab + 0, h1);
  hipLaunchKernelGGL(conv2_half, dim3(2048), dim3(256), 0, stream,
                     h1, wb2, ab + 64, h2);
  hipLaunchKernelGGL(conv3_pad, dim3(512), dim3(256), 0, stream,
                     h2, wb3, ab + 192, h3);
  hipLaunchKernelGGL(conv4_mfma, dim3(512), dim3(512), 0, stream,
                     h3, wb4, ab + 448, h4h, h4l);
  hipLaunchKernelGGL((fc_mfma<2, 2, 18, 256>), dim3(4, 144), dim3(256), 0, stream,
                     h4h, h4l, wb5, ab + 960, nullptr, h5h, h5l);

  // 4) FC stack
  hipLaunchKernelGGL((fc_mfma<18, 0, 8, 1024>), dim3(16, 16), dim3(256), 0, stream,
                     h5h, h5l, fqb1, ab + 1472, nullptr, f1h, f1l);
  hipLaunchKernelGGL((fc_mfma<8, 1, 0, 512>), dim3(8, 16), dim3(256), 0, stream,
                     f1h, f1l, fqb2, ab + 3520, f2, nullptr, nullptr);
  hipLaunchKernelGGL(fc3_kernel, dim3(64), dim3(256), 0, stream,
                     f2, fq3, (const float*)d_in[44], (float*)d_out);
}